// Round 2
// baseline (2121.131 us; speedup 1.0000x reference)
//
#include <hip/hip_runtime.h>

typedef unsigned short ushort_t;
typedef unsigned int uint_t;
typedef unsigned long long ull_t;
typedef __attribute__((ext_vector_type(8))) short short8;
typedef __attribute__((ext_vector_type(4))) float f32x4;

#define B_ 1024
#define N_ 64
#define H_ 128
#define NT 256

// bf16 weight-image element offsets
#define IMG_WI 0
#define IMG_WJ 16384
#define IMG_UW 32768
#define IMG_GS 49152
#define IMG_FT 65536
#define IMG_FB 81920
#define IMG_C1 98304
#define IMG_C2 163840
#define IMG_GMT 229376
#define IMG_RW 245760
#define IMG_L 249856
#define IMG_FO 999424
#define WS_WEIGHTS (2u*1024u*1024u)
#define KNN_STRIDE 12288u

__device__ __forceinline__ ushort_t f2bf(float f) {
    uint_t u = __float_as_uint(f);
    return (ushort_t)((u + 0x7fffu + ((u >> 16) & 1u)) >> 16);
}
__device__ __forceinline__ float bf2f(ushort_t u) {
    union { uint_t i; float f; } v; v.i = ((uint_t)u) << 16; return v.f;
}
__device__ __forceinline__ float siluf(float x) { return x / (1.0f + __expf(-x)); }

// LDS swizzle: 16B-chunk c of row m stored at chunk c ^ (m&7)
__device__ __forceinline__ int sidx(int m, int k) {
    return m * H_ + (((k >> 3) ^ (m & 7)) << 3) + (k & 7);
}
__device__ __forceinline__ int fragoff(int m, int ch) {
    return m * H_ + ((ch ^ (m & 7)) << 3);
}

// ========== preamble 1: f32 weights -> transposed bf16 images ==============
extern "C" __global__ __launch_bounds__(256)
void convert_weights(const float* __restrict__ msg_W, const float* __restrict__ upd_W,
                     const float* __restrict__ gself_W, const float* __restrict__ fus_W,
                     const float* __restrict__ cb_W1, const float* __restrict__ cb_W2,
                     const float* __restrict__ gmean_W, const float* __restrict__ fo_W1,
                     ushort_t* __restrict__ wimg)
{
    const int g = blockIdx.x;
    if (g >= 244) {
        int st = g - 244;
        ushort_t* dst = wimg + IMG_FO + st * 4096;
        for (int e = 0; e < 16; ++e) {
            int q = threadIdx.x * 16 + e;
            int n = q >> 7, k = q & 127;
            dst[q] = f2bf(fo_W1[(size_t)k * 128 + st * 32 + n]);
        }
        return;
    }
    const int l = g / 61, r = g - l * 61;
    ushort_t* base = wimg + l * IMG_L;
    if (r == 60) {                       // rW pad image: 4 sub-stages [32f][32k]
        const float* W = msg_W + l * 35328 + 256 * 128;
        ushort_t* dst = base + IMG_RW;
        for (int e = 0; e < 16; ++e) {
            int q = threadIdx.x * 16 + e;
            int sub = q >> 10, n = (q >> 5) & 31, k = q & 31;
            dst[q] = f2bf(k < 20 ? W[(size_t)k * 128 + sub * 32 + n] : 0.0f);
        }
        return;
    }
    const float* W; int ld = 128, k0 = 0, c0, off, st;
    if      (r < 4)  { W = msg_W + l * 35328;            st = r;      off = IMG_WI;  c0 = st * 32; }
    else if (r < 8)  { W = msg_W + l * 35328;  k0 = 128; st = r - 4;  off = IMG_WJ;  c0 = st * 32; }
    else if (r < 12) { W = upd_W + l * 16384;            st = r - 8;  off = IMG_UW;  c0 = st * 32; }
    else if (r < 16) { W = gself_W + l * 16384;          st = r - 12; off = IMG_GS;  c0 = st * 32; }
    else if (r < 20) { W = fus_W + l * 32768;            st = r - 16; off = IMG_FT;  c0 = st * 32; }
    else if (r < 24) { W = fus_W + l * 32768;  k0 = 128; st = r - 20; off = IMG_FB;  c0 = st * 32; }
    else if (r < 40) { W = cb_W1 + l * 65536;  ld = 512; st = r - 24; off = IMG_C1;  c0 = st * 32; }
    else if (r < 56) { int j = (r - 40) >> 2; W = cb_W2 + l * 65536; k0 = j * 128;
                       st = r - 40; off = IMG_C2; c0 = ((r - 40) & 3) * 32; }
    else             { W = gmean_W + l * 16384;          st = r - 56; off = IMG_GMT; c0 = st * 32; }
    ushort_t* dst = base + off + st * 4096;
    for (int e = 0; e < 16; ++e) {
        int q = threadIdx.x * 16 + e;
        int n = q >> 7, k = q & 127;
        dst[q] = f2bf(W[(size_t)(k0 + k) * ld + c0 + n]);
    }
}

// ========== preamble 2: kNN per graph (1 wave), validated logic ============
extern "C" __global__ __launch_bounds__(64)
void knn_kernel(const float* __restrict__ positions, char* __restrict__ ws)
{
    const int b = blockIdx.x, lane = threadIdx.x;
    float px = positions[b * 192 + lane * 3 + 0];
    float py = positions[b * 192 + lane * 3 + 1];
    float pz = positions[b * 192 + lane * 3 + 2];
    float* kd = (float*)(ws + WS_WEIGHTS + (size_t)b * KNN_STRIDE);
    float* ke = kd + 1024;
    ushort_t* ki = (ushort_t*)(ke + 1024);
    for (int n = 0; n < 64; ++n) {
        float dx = __fsub_rn(__shfl(px, n), px);
        float dy = __fsub_rn(__shfl(py, n), py);
        float dz = __fsub_rn(__shfl(pz, n), pz);
        float d2 = __fadd_rn(__fadd_rn(__fmul_rn(dx, dx), __fmul_rn(dy, dy)), __fmul_rn(dz, dz));
        if (lane == n) d2 = 1e30f;
        float sd = 0.f; int si = 0;
        for (int k = 0; k < 16; ++k) {
            float dmin = d2;
            #pragma unroll
            for (int o = 1; o < 64; o <<= 1) dmin = fminf(dmin, __shfl_xor(dmin, o));
            ull_t mask = __ballot(d2 == dmin);
            int widx = __ffsll(mask) - 1;       // lowest index on ties (= top_k)
            if (lane == widx) d2 = 1e30f;
            if (lane == k) { si = widx; sd = dmin; }
        }
        if (lane < 16) {
            float dd = sqrtf(fmaxf(sd, 1e-12f));
            kd[n * 16 + lane] = dd;
            ke[n * 16 + lane] = (dd < 5.0f) ? 0.5f * (__cosf(0.62831853071795864769f * dd) + 1.0f) : 0.0f;
            ki[n * 16 + lane] = (ushort_t)si;
        }
    }
}

// ========== main fused kernel ==============================================
// 256 threads = 4 waves; wave w owns rows w*16..w*16+15 (ALL 128 cols).
// Residual stream in REGISTERS (hreg[8][4], C-frag layout). LDS = 45056 B
// -> 3 blocks/CU. NO min-waves launch_bounds arg: (256,W) empirically caps
// arch VGPRs at 256/W (W=3 gave 84 regs -> 190 spill slots -> 8x HBM traffic).
struct __align__(16) Smem {
    ushort_t T1[N_ * H_];   // 16384B
    ushort_t T2[N_ * H_];   // 16384B
    float d[1024];          //  4096B
    float env[1024];        //  4096B
    ushort_t idx[1024];     //  2048B
    char u[2048];           // union: spos(768) | {part bf16 1024, hmean 512, gvec 512}
};

// one output stage s (16 cols, col = s*16+l15), K=128: 4 B-frags from global
__device__ __forceinline__ f32x4 gemm_s(const short8 a[4], const ushort_t* __restrict__ img,
                                        int s, int l15, int quad)
{
    const ushort_t* base = img + ((s >> 1) << 12) + ((((s & 1) << 4) + l15) << 7) + quad * 8;
    short8 b0 = *(const short8*)(base);
    short8 b1 = *(const short8*)(base + 32);
    short8 b2 = *(const short8*)(base + 64);
    short8 b3 = *(const short8*)(base + 96);
    f32x4 c = {0.f, 0.f, 0.f, 0.f};
    c = __builtin_amdgcn_mfma_f32_16x16x32_bf16(a[0], b0, c, 0, 0, 0);
    c = __builtin_amdgcn_mfma_f32_16x16x32_bf16(a[1], b1, c, 0, 0, 0);
    c = __builtin_amdgcn_mfma_f32_16x16x32_bf16(a[2], b2, c, 0, 0, 0);
    c = __builtin_amdgcn_mfma_f32_16x16x32_bf16(a[3], b3, c, 0, 0, 0);
    return c;
}
__device__ __forceinline__ f32x4 gemm_s_acc(const short8 a[4], const ushort_t* __restrict__ img,
                                            int s, int l15, int quad, f32x4 c)
{
    const ushort_t* base = img + ((s >> 1) << 12) + ((((s & 1) << 4) + l15) << 7) + quad * 8;
    short8 b0 = *(const short8*)(base);
    short8 b1 = *(const short8*)(base + 32);
    short8 b2 = *(const short8*)(base + 64);
    short8 b3 = *(const short8*)(base + 96);
    c = __builtin_amdgcn_mfma_f32_16x16x32_bf16(a[0], b0, c, 0, 0, 0);
    c = __builtin_amdgcn_mfma_f32_16x16x32_bf16(a[1], b1, c, 0, 0, 0);
    c = __builtin_amdgcn_mfma_f32_16x16x32_bf16(a[2], b2, c, 0, 0, 0);
    c = __builtin_amdgcn_mfma_f32_16x16x32_bf16(a[3], b3, c, 0, 0, 0);
    return c;
}
__device__ __forceinline__ void loadA(const ushort_t* __restrict__ X, int mrow, int quad, short8 a[4]) {
    #pragma unroll
    for (int kc = 0; kc < 4; ++kc) a[kc] = *(const short8*)&X[fragoff(mrow, kc * 4 + quad)];
}

extern "C" __global__ __launch_bounds__(NT)
void md17_fused_kernel(
    const float* __restrict__ positions, const int* __restrict__ atomic_numbers,
    const float* __restrict__ atom_embed, const float* __restrict__ pos_W,
    const float* __restrict__ pos_b,
    const float* __restrict__ msg_b, const float* __restrict__ upd_b,
    const float* __restrict__ g_b, const float* __restrict__ fus_b,
    const float* __restrict__ ln_g, const float* __restrict__ ln_b,
    const float* __restrict__ cb_b1, const float* __restrict__ cb_b2,
    const float* __restrict__ fo_b1,
    const float* __restrict__ fo_W2, const float* __restrict__ fo_b2,
    char* __restrict__ ws, float* __restrict__ out)
{
    __shared__ Smem sm;
    const int b = blockIdx.x;
    const int tid = threadIdx.x;
    const int wave = tid >> 6, lane = tid & 63;
    const int quad = lane >> 4, l15 = lane & 15;
    const int mrow = wave * 16 + l15;       // A-frag row (wave-owned)
    const int rbase = wave * 16 + quad * 4; // C-tile row base (wave-owned)

    const ushort_t* wimg = (const ushort_t*)ws;
    float* spos = (float*)sm.u;
    ushort_t* part = (ushort_t*)sm.u;       // [4][128] bf16 hmean partials
    float* hmean = (float*)(sm.u + 1024);
    float* gvec  = (float*)(sm.u + 1536);

    // residual stream, C-frag layout: hreg[s][r] = h[rbase+r][s*16+l15]
    float hreg[8][4];

    // ---- setup: kNN blob, positions ----
    {
        const char* kb = ws + WS_WEIGHTS + (size_t)b * KNN_STRIDE;
        const float* kd = (const float*)kb;
        const float* ke = (const float*)(kb + 4096);
        const uint_t* ki = (const uint_t*)(kb + 8192);
        for (int t = tid; t < 1024; t += NT) { sm.d[t] = kd[t]; sm.env[t] = ke[t]; }
        for (int t = tid; t < 512; t += NT) ((uint_t*)sm.idx)[t] = ki[t];
        if (tid < 192) spos[tid] = positions[b * 192 + tid];
    }
    __syncthreads();
    // ---- embeddings, per-lane into hreg + T1 image ----
    {
        int an[4];
        #pragma unroll
        for (int r = 0; r < 4; ++r) an[r] = atomic_numbers[b * N_ + rbase + r];
        #pragma unroll
        for (int s = 0; s < 8; ++s) {
            int col = s * 16 + l15;
            #pragma unroll
            for (int r = 0; r < 4; ++r) {
                float v;
                if (s < 2) {                        // col < 32: atom-type embed
                    v = atom_embed[an[r] * 32 + col];
                } else {                            // col >= 32: position MLP
                    int j = col - 32;
                    v = pos_b[j];
                    #pragma unroll
                    for (int c = 0; c < 3; ++c)
                        v = fmaf(spos[(rbase + r) * 3 + c], pos_W[c * 96 + j], v);
                }
                hreg[s][r] = v;
                sm.T1[sidx(rbase + r, col)] = f2bf(v);
            }
        }
    }
    __syncthreads();

    #pragma unroll 1
    for (int l = 0; l < 4; ++l) {
        const ushort_t* wl = wimg + l * IMG_L;
        const float* mb  = msg_b + l * H_;
        const float* ub  = upd_b + l * H_;
        const float* gb  = g_b + l * H_;
        const float* fb  = fus_b + l * H_;
        const float* lg  = ln_g + l * H_;
        const float* lb  = ln_b + l * H_;
        const float* c1b = cb_b1 + l * 4 * H_;
        const float* c2b = cb_b2 + l * H_;

        // A: hmean partials over own 16 rows (from hreg)
        #pragma unroll
        for (int s = 0; s < 8; ++s) {
            int col = s * 16 + l15;
            float p = hreg[s][0] + hreg[s][1] + hreg[s][2] + hreg[s][3];
            p += __shfl_xor(p, 16);
            p += __shfl_xor(p, 32);
            if (quad == 0) part[wave * 128 + col] = f2bf(p);
        }
        __syncthreads();                                 // B1
        if (tid < H_)
            hmean[tid] = (bf2f(part[tid]) + bf2f(part[128 + tid])
                        + bf2f(part[256 + tid]) + bf2f(part[384 + tid])) * (1.0f / 64.0f);
        __syncthreads();                                 // B2

        // C: gvec GEMV (tid<128) ; a_h ; WI -> T1 (+mb) ; WJ -> T2
        short8 a_h[4];                                   // h image, own rows (kept live -> GS)
        if (tid < H_) {
            float s = gb[tid];
            const ushort_t* wrow = wl + IMG_GMT + tid * 128;
            for (int c = 0; c < 128; c += 8) {
                short8 w = *(const short8*)(wrow + c);
                #pragma unroll
                for (int i = 0; i < 8; ++i) s = fmaf(hmean[c + i], bf2f((ushort_t)w[i]), s);
            }
            gvec[tid] = s;
        }
        {
            loadA(sm.T1, mrow, quad, a_h);
            #pragma unroll
            for (int s = 0; s < 8; ++s) {
                f32x4 c = gemm_s(a_h, wl + IMG_WI, s, l15, quad);
                int col = s * 16 + l15; float bv = mb[col];
                #pragma unroll
                for (int r = 0; r < 4; ++r)
                    sm.T1[sidx(rbase + r, col)] = f2bf(c[r] + bv);
            }
            #pragma unroll
            for (int s = 0; s < 8; ++s) {
                f32x4 c = gemm_s(a_h, wl + IMG_WJ, s, l15, quad);
                int col = s * 16 + l15;
                #pragma unroll
                for (int r = 0; r < 4; ++r)
                    sm.T2[sidx(rbase + r, col)] = f2bf(c[r]);
            }
        }
        __syncthreads();                                 // B3 (Gm visible to all)

        // D: msum — whole wave per atom n = wave*16+g (own rows), in place in T1
        {
            float ccv[8];
            #pragma unroll
            for (int j = 0; j < 8; ++j)
                ccv[j] = (float)((double)(quad * 8 + j) * (5.0 / 19.0));
            #pragma unroll 1
            for (int g = 0; g < 16; ++g) {
                int n = wave * 16 + g;
                int jv[4]; float ev[4];
                #pragma unroll
                for (int r = 0; r < 4; ++r) {
                    int k = quad * 4 + r;
                    jv[r] = sm.idx[n * 16 + k];
                    ev[r] = sm.env[n * 16 + k];
                }
                float ddm = sm.d[n * 16 + l15];
                short8 arb;
                #pragma unroll
                for (int j = 0; j < 8; ++j) {
                    float t2 = ddm - ccv[j];
                    float rv = __expf(-10.0f * t2 * t2);
                    arb[j] = (short)((quad * 8 + j) < 20 ? f2bf(rv) : (ushort_t)0);
                }
                #pragma unroll
                for (int s = 0; s < 8; ++s) {
                    int col = s * 16 + l15;
                    const ushort_t* rbase_p = wl + IMG_RW + ((s >> 1) << 10)
                                            + ((((s & 1) << 4) + l15) << 5) + quad * 8;
                    short8 brw = *(const short8*)rbase_p;
                    f32x4 c = {0.f, 0.f, 0.f, 0.f};
                    c = __builtin_amdgcn_mfma_f32_16x16x32_bf16(arb, brw, c, 0, 0, 0);
                    float ai = bf2f(sm.T1[sidx(n, col)]);
                    float acc = 0.f;
                    #pragma unroll
                    for (int r = 0; r < 4; ++r) {
                        float gm = bf2f(sm.T2[sidx(jv[r], col)]);
                        acc = fmaf(siluf(ai + gm + c[r]), ev[r], acc);
                    }
                    acc += __shfl_xor(acc, 16);
                    acc += __shfl_xor(acc, 32);
                    if (quad == 0) sm.T1[sidx(n, col)] = f2bf(acc);
                }
            }
        }
        __syncthreads();                                 // B4 (Gm reads done; T2 free)

        // ---- free-run region: everything below touches only own rows ----

        // F: UW(a_m)+hreg -> T2 local ; GS(a_h, kept from C) + gvec -> T1 glob
        {
            short8 a_m[4]; loadA(sm.T1, mrow, quad, a_m);
            #pragma unroll
            for (int s = 0; s < 8; ++s) {
                f32x4 c = gemm_s(a_m, wl + IMG_UW, s, l15, quad);
                int col = s * 16 + l15; float bv = ub[col];
                #pragma unroll
                for (int r = 0; r < 4; ++r)
                    sm.T2[sidx(rbase + r, col)] = f2bf(hreg[s][r] + siluf(c[r] + bv));
            }
            #pragma unroll
            for (int s = 0; s < 8; ++s) {
                f32x4 c = gemm_s(a_h, wl + IMG_GS, s, l15, quad);
                int col = s * 16 + l15; float gv = gvec[col];
                #pragma unroll
                for (int r = 0; r < 4; ++r)
                    sm.T1[sidx(rbase + r, col)] = f2bf(siluf(c[r] + gv));
            }
        }

        // G: fused = silu([local|glob]@[FT;FB]+fb) -> hreg ; LN sums in regs
        float sr[4] = {0.f, 0.f, 0.f, 0.f}, qr[4] = {0.f, 0.f, 0.f, 0.f};
        {
            short8 a_t[4];
            loadA(sm.T2, mrow, quad, a_t);               // local
            #pragma unroll
            for (int s = 0; s < 8; ++s) {
                f32x4 c = gemm_s(a_t, wl + IMG_FT, s, l15, quad);
                #pragma unroll
                for (int r = 0; r < 4; ++r) hreg[s][r] = c[r];  // residual h is dead here
            }
            loadA(sm.T1, mrow, quad, a_t);               // glob
            #pragma unroll
            for (int s = 0; s < 8; ++s) {
                f32x4 c = gemm_s(a_t, wl + IMG_FB, s, l15, quad);
                int col = s * 16 + l15; float bv = fb[col];
                #pragma unroll
                for (int r = 0; r < 4; ++r) {
                    float v = siluf(hreg[s][r] + c[r] + bv);
                    hreg[s][r] = v;
                    sr[r] += v; qr[r] += v * v;
                }
            }
            #pragma unroll
            for (int o = 1; o < 16; o <<= 1) {
                #pragma unroll
                for (int r = 0; r < 4; ++r) {
                    sr[r] += __shfl_xor(sr[r], o);
                    qr[r] += __shfl_xor(qr[r], o);
                }
            }
        }

        // H: LN normalize (wave-local) -> T1 (x-hat)
        #pragma unroll
        for (int r = 0; r < 4; ++r) {
            float mu = sr[r] * (1.0f / 128.0f);
            float var = qr[r] * (1.0f / 128.0f) - mu * mu;
            float rs = rsqrtf(var + 1e-5f);
            int row = rbase + r;
            #pragma unroll
            for (int s = 0; s < 8; ++s) {
                int col = s * 16 + l15;
                sm.T1[sidx(row, col)] = f2bf((hreg[s][r] - mu) * rs * lg[col] + lb[col]);
            }
        }

        // J: Clifford MLP, 4 K-chunks; C1 -> T2; C2 accumulates into acc2.
        // acc2 is SEEDED with residual + c2b so hreg is dead across the whole
        // j-loop (cuts 32 live VGPRs from the peak-pressure region).
        {
            short8 a_x[4]; loadA(sm.T1, mrow, quad, a_x);
            f32x4 acc2[8];
            #pragma unroll
            for (int s = 0; s < 8; ++s) {
                int col = s * 16 + l15; float bv = c2b[col];
                #pragma unroll
                for (int r = 0; r < 4; ++r) acc2[s][r] = hreg[s][r] + bv;
            }
            #pragma unroll 1
            for (int j = 0; j < 4; ++j) {
                #pragma unroll
                for (int s = 0; s < 8; ++s) {
                    f32x4 c = gemm_s(a_x, wl + IMG_C1 + j * 16384, s, l15, quad);
                    int col = s * 16 + l15; float bv = c1b[j * H_ + col];
                    #pragma unroll
                    for (int r = 0; r < 4; ++r)
                        sm.T2[sidx(rbase + r, col)] = f2bf(siluf(c[r] + bv));
                }
                short8 a_t[4]; loadA(sm.T2, mrow, quad, a_t);
                #pragma unroll
                for (int s = 0; s < 8; ++s)
                    acc2[s] = gemm_s_acc(a_t, wl + IMG_C2 + j * 16384, s, l15, quad, acc2[s]);
            }
            // K: h_next = acc2 (residual+bias already inside) -> hreg + T1 image
            #pragma unroll
            for (int s = 0; s < 8; ++s) {
                #pragma unroll
                for (int r = 0; r < 4; ++r) {
                    float v = acc2[s][r];
                    hreg[s][r] = v;
                    sm.T1[sidx(rbase + r, s * 16 + l15)] = f2bf(v);
                }
            }
        }
        // no layer-end barrier: next stage A reads only own rows/regs
    }

    // ---- head: FO -> T2 (own rows, no barrier) ; barrier ; gather -> out ----
    {
        short8 a_f[4]; loadA(sm.T1, mrow, quad, a_f);
        #pragma unroll
        for (int s = 0; s < 8; ++s) {
            f32x4 c = gemm_s(a_f, wimg + IMG_FO, s, l15, quad);
            int col = s * 16 + l15; float bv = fo_b1[col];
            #pragma unroll
            for (int r = 0; r < 4; ++r)
                sm.T2[sidx(rbase + r, col)] = f2bf(siluf(c[r] + bv));
        }
    }
    __syncthreads();
    if (tid < 192) {
        int n = tid / 3, j = tid - n * 3;
        float s = fo_b2[j];
        #pragma unroll 1
        for (int ch = 0; ch < 16; ++ch) {
            short8 v = *(const short8*)&sm.T2[fragoff(n, ch)];
            #pragma unroll
            for (int i = 0; i < 8; ++i)
                s = fmaf(bf2f((ushort_t)v[i]), fo_W2[(ch * 8 + i) * 3 + j], s);
        }
        out[b * 192 + tid] = s;
    }
}

extern "C" void kernel_launch(void* const* d_in, const int* in_sizes, int n_in,
                              void* d_out, int out_size, void* d_ws, size_t ws_size,
                              hipStream_t stream) {
    (void)in_sizes; (void)n_in; (void)out_size; (void)ws_size;
    convert_weights<<<248, 256, 0, stream>>>(
        (const float*)d_in[5], (const float*)d_in[7], (const float*)d_in[9],
        (const float*)d_in[12], (const float*)d_in[16], (const float*)d_in[18],
        (const float*)d_in[10], (const float*)d_in[20], (ushort_t*)d_ws);
    knn_kernel<<<B_, 64, 0, stream>>>((const float*)d_in[0], (char*)d_ws);
    md17_fused_kernel<<<B_, NT, 0, stream>>>(
        (const float*)d_in[0], (const int*)d_in[1],
        (const float*)d_in[2], (const float*)d_in[3], (const float*)d_in[4],
        (const float*)d_in[6], (const float*)d_in[8],
        (const float*)d_in[11], (const float*)d_in[13],
        (const float*)d_in[14], (const float*)d_in[15],
        (const float*)d_in[17], (const float*)d_in[19],
        (const float*)d_in[21],
        (const float*)d_in[22], (const float*)d_in[23],
        (char*)d_ws, (float*)d_out);
}

// Round 3
// 1433.807 us; speedup vs baseline: 1.4794x; 1.4794x over previous
//
#include <hip/hip_runtime.h>

typedef unsigned short ushort_t;
typedef unsigned int uint_t;
typedef unsigned long long ull_t;
typedef __attribute__((ext_vector_type(8))) short short8;
typedef __attribute__((ext_vector_type(4))) float f32x4;

#define B_ 1024
#define N_ 64
#define H_ 128
#define NT 256

// bf16 weight-image element offsets
#define IMG_WI 0
#define IMG_WJ 16384
#define IMG_UW 32768
#define IMG_GS 49152
#define IMG_FT 65536
#define IMG_FB 81920
#define IMG_C1 98304
#define IMG_C2 163840
#define IMG_GMT 229376
#define IMG_RW 245760
#define IMG_L 249856
#define IMG_FO 999424
#define WS_WEIGHTS (2u*1024u*1024u)
#define KNN_STRIDE 12288u

__device__ __forceinline__ ushort_t f2bf(float f) {
    uint_t u = __float_as_uint(f);
    return (ushort_t)((u + 0x7fffu + ((u >> 16) & 1u)) >> 16);
}
__device__ __forceinline__ float bf2f(ushort_t u) {
    union { uint_t i; float f; } v; v.i = ((uint_t)u) << 16; return v.f;
}
__device__ __forceinline__ float siluf(float x) { return x / (1.0f + __expf(-x)); }

// LDS swizzle: 16B-chunk c of row m stored at chunk c ^ (m&7)
__device__ __forceinline__ int sidx(int m, int k) {
    return m * H_ + (((k >> 3) ^ (m & 7)) << 3) + (k & 7);
}
__device__ __forceinline__ int fragoff(int m, int ch) {
    return m * H_ + ((ch ^ (m & 7)) << 3);
}

// ========== preamble 1: f32 weights -> transposed bf16 images ==============
extern "C" __global__ __launch_bounds__(256)
void convert_weights(const float* __restrict__ msg_W, const float* __restrict__ upd_W,
                     const float* __restrict__ gself_W, const float* __restrict__ fus_W,
                     const float* __restrict__ cb_W1, const float* __restrict__ cb_W2,
                     const float* __restrict__ gmean_W, const float* __restrict__ fo_W1,
                     ushort_t* __restrict__ wimg)
{
    const int g = blockIdx.x;
    if (g >= 244) {
        int st = g - 244;
        ushort_t* dst = wimg + IMG_FO + st * 4096;
        for (int e = 0; e < 16; ++e) {
            int q = threadIdx.x * 16 + e;
            int n = q >> 7, k = q & 127;
            dst[q] = f2bf(fo_W1[(size_t)k * 128 + st * 32 + n]);
        }
        return;
    }
    const int l = g / 61, r = g - l * 61;
    ushort_t* base = wimg + l * IMG_L;
    if (r == 60) {                       // rW pad image: 4 sub-stages [32f][32k]
        const float* W = msg_W + l * 35328 + 256 * 128;
        ushort_t* dst = base + IMG_RW;
        for (int e = 0; e < 16; ++e) {
            int q = threadIdx.x * 16 + e;
            int sub = q >> 10, n = (q >> 5) & 31, k = q & 31;
            dst[q] = f2bf(k < 20 ? W[(size_t)k * 128 + sub * 32 + n] : 0.0f);
        }
        return;
    }
    const float* W; int ld = 128, k0 = 0, c0, off, st;
    if      (r < 4)  { W = msg_W + l * 35328;            st = r;      off = IMG_WI;  c0 = st * 32; }
    else if (r < 8)  { W = msg_W + l * 35328;  k0 = 128; st = r - 4;  off = IMG_WJ;  c0 = st * 32; }
    else if (r < 12) { W = upd_W + l * 16384;            st = r - 8;  off = IMG_UW;  c0 = st * 32; }
    else if (r < 16) { W = gself_W + l * 16384;          st = r - 12; off = IMG_GS;  c0 = st * 32; }
    else if (r < 20) { W = fus_W + l * 32768;            st = r - 16; off = IMG_FT;  c0 = st * 32; }
    else if (r < 24) { W = fus_W + l * 32768;  k0 = 128; st = r - 20; off = IMG_FB;  c0 = st * 32; }
    else if (r < 40) { W = cb_W1 + l * 65536;  ld = 512; st = r - 24; off = IMG_C1;  c0 = st * 32; }
    else if (r < 56) { int j = (r - 40) >> 2; W = cb_W2 + l * 65536; k0 = j * 128;
                       st = r - 40; off = IMG_C2; c0 = ((r - 40) & 3) * 32; }
    else             { W = gmean_W + l * 16384;          st = r - 56; off = IMG_GMT; c0 = st * 32; }
    ushort_t* dst = base + off + st * 4096;
    for (int e = 0; e < 16; ++e) {
        int q = threadIdx.x * 16 + e;
        int n = q >> 7, k = q & 127;
        dst[q] = f2bf(W[(size_t)(k0 + k) * ld + c0 + n]);
    }
}

// ========== preamble 2: kNN per graph (1 wave), validated logic ============
extern "C" __global__ __launch_bounds__(64)
void knn_kernel(const float* __restrict__ positions, char* __restrict__ ws)
{
    const int b = blockIdx.x, lane = threadIdx.x;
    float px = positions[b * 192 + lane * 3 + 0];
    float py = positions[b * 192 + lane * 3 + 1];
    float pz = positions[b * 192 + lane * 3 + 2];
    float* kd = (float*)(ws + WS_WEIGHTS + (size_t)b * KNN_STRIDE);
    float* ke = kd + 1024;
    ushort_t* ki = (ushort_t*)(ke + 1024);
    for (int n = 0; n < 64; ++n) {
        float dx = __fsub_rn(__shfl(px, n), px);
        float dy = __fsub_rn(__shfl(py, n), py);
        float dz = __fsub_rn(__shfl(pz, n), pz);
        float d2 = __fadd_rn(__fadd_rn(__fmul_rn(dx, dx), __fmul_rn(dy, dy)), __fmul_rn(dz, dz));
        if (lane == n) d2 = 1e30f;
        float sd = 0.f; int si = 0;
        for (int k = 0; k < 16; ++k) {
            float dmin = d2;
            #pragma unroll
            for (int o = 1; o < 64; o <<= 1) dmin = fminf(dmin, __shfl_xor(dmin, o));
            ull_t mask = __ballot(d2 == dmin);
            int widx = __ffsll(mask) - 1;       // lowest index on ties (= top_k)
            if (lane == widx) d2 = 1e30f;
            if (lane == k) { si = widx; sd = dmin; }
        }
        if (lane < 16) {
            float dd = sqrtf(fmaxf(sd, 1e-12f));
            kd[n * 16 + lane] = dd;
            ke[n * 16 + lane] = (dd < 5.0f) ? 0.5f * (__cosf(0.62831853071795864769f * dd) + 1.0f) : 0.0f;
            ki[n * 16 + lane] = (ushort_t)si;
        }
    }
}

// ========== main fused kernel ==============================================
// 256 threads = 4 waves; wave w owns rows w*16..w*16+15 (ALL 128 cols).
// Residual stream in REGISTERS (hreg[8][4], C-frag layout).
// T3 holds the layer-input h image so NO A-fragment stays live across long
// stages (a_h reloaded at GS; a_x reloaded per Clifford chunk).
// Register budget: gfx950 unified VGPR+AGPR; __launch_bounds__(NT,2) pins
// total <= 256/wave -> 2 blocks/CU with (predicted) ~zero spill.
// History: (NT,3)=170 cap -> 190-slot spill, 8x HBM; uncapped -> >256 total
// -> 1 block/CU (12% occ). LDS 61440 -> 2 blocks/CU (122880 <= 160K).
struct __align__(16) Smem {
    ushort_t T1[N_ * H_];   // 16384B  scratch image (Gm/msum/glob/xhat)
    ushort_t T2[N_ * H_];   // 16384B  scratch image (hj/local/C1)
    ushort_t T3[N_ * H_];   // 16384B  layer-input h image
    float d[1024];          //  4096B
    float env[1024];        //  4096B
    ushort_t idx[1024];     //  2048B
    char u[2048];           // union: spos(768) | {part bf16 1024, hmean 512, gvec 512}
};

// one output stage s (16 cols, col = s*16+l15), K=128: 4 B-frags from global
__device__ __forceinline__ f32x4 gemm_s(const short8 a[4], const ushort_t* __restrict__ img,
                                        int s, int l15, int quad)
{
    const ushort_t* base = img + ((s >> 1) << 12) + ((((s & 1) << 4) + l15) << 7) + quad * 8;
    short8 b0 = *(const short8*)(base);
    short8 b1 = *(const short8*)(base + 32);
    short8 b2 = *(const short8*)(base + 64);
    short8 b3 = *(const short8*)(base + 96);
    f32x4 c = {0.f, 0.f, 0.f, 0.f};
    c = __builtin_amdgcn_mfma_f32_16x16x32_bf16(a[0], b0, c, 0, 0, 0);
    c = __builtin_amdgcn_mfma_f32_16x16x32_bf16(a[1], b1, c, 0, 0, 0);
    c = __builtin_amdgcn_mfma_f32_16x16x32_bf16(a[2], b2, c, 0, 0, 0);
    c = __builtin_amdgcn_mfma_f32_16x16x32_bf16(a[3], b3, c, 0, 0, 0);
    return c;
}
__device__ __forceinline__ f32x4 gemm_s_acc(const short8 a[4], const ushort_t* __restrict__ img,
                                            int s, int l15, int quad, f32x4 c)
{
    const ushort_t* base = img + ((s >> 1) << 12) + ((((s & 1) << 4) + l15) << 7) + quad * 8;
    short8 b0 = *(const short8*)(base);
    short8 b1 = *(const short8*)(base + 32);
    short8 b2 = *(const short8*)(base + 64);
    short8 b3 = *(const short8*)(base + 96);
    c = __builtin_amdgcn_mfma_f32_16x16x32_bf16(a[0], b0, c, 0, 0, 0);
    c = __builtin_amdgcn_mfma_f32_16x16x32_bf16(a[1], b1, c, 0, 0, 0);
    c = __builtin_amdgcn_mfma_f32_16x16x32_bf16(a[2], b2, c, 0, 0, 0);
    c = __builtin_amdgcn_mfma_f32_16x16x32_bf16(a[3], b3, c, 0, 0, 0);
    return c;
}
__device__ __forceinline__ void loadA(const ushort_t* __restrict__ X, int mrow, int quad, short8 a[4]) {
    #pragma unroll
    for (int kc = 0; kc < 4; ++kc) a[kc] = *(const short8*)&X[fragoff(mrow, kc * 4 + quad)];
}

extern "C" __global__ __launch_bounds__(NT, 2)
void md17_fused_kernel(
    const float* __restrict__ positions, const int* __restrict__ atomic_numbers,
    const float* __restrict__ atom_embed, const float* __restrict__ pos_W,
    const float* __restrict__ pos_b,
    const float* __restrict__ msg_b, const float* __restrict__ upd_b,
    const float* __restrict__ g_b, const float* __restrict__ fus_b,
    const float* __restrict__ ln_g, const float* __restrict__ ln_b,
    const float* __restrict__ cb_b1, const float* __restrict__ cb_b2,
    const float* __restrict__ fo_b1,
    const float* __restrict__ fo_W2, const float* __restrict__ fo_b2,
    char* __restrict__ ws, float* __restrict__ out)
{
    __shared__ Smem sm;
    const int b = blockIdx.x;
    const int tid = threadIdx.x;
    const int wave = tid >> 6, lane = tid & 63;
    const int quad = lane >> 4, l15 = lane & 15;
    const int mrow = wave * 16 + l15;       // A-frag row (wave-owned)
    const int rbase = wave * 16 + quad * 4; // C-tile row base (wave-owned)

    const ushort_t* wimg = (const ushort_t*)ws;
    float* spos = (float*)sm.u;
    ushort_t* part = (ushort_t*)sm.u;       // [4][128] bf16 hmean partials
    float* hmean = (float*)(sm.u + 1024);
    float* gvec  = (float*)(sm.u + 1536);

    // residual stream, C-frag layout: hreg[s][r] = h[rbase+r][s*16+l15]
    float hreg[8][4];

    // ---- setup: kNN blob, positions ----
    {
        const char* kb = ws + WS_WEIGHTS + (size_t)b * KNN_STRIDE;
        const float* kd = (const float*)kb;
        const float* ke = (const float*)(kb + 4096);
        const uint_t* ki = (const uint_t*)(kb + 8192);
        for (int t = tid; t < 1024; t += NT) { sm.d[t] = kd[t]; sm.env[t] = ke[t]; }
        for (int t = tid; t < 512; t += NT) ((uint_t*)sm.idx)[t] = ki[t];
        if (tid < 192) spos[tid] = positions[b * 192 + tid];
    }
    __syncthreads();
    // ---- embeddings, per-lane into hreg + T3 image ----
    {
        int an[4];
        #pragma unroll
        for (int r = 0; r < 4; ++r) an[r] = atomic_numbers[b * N_ + rbase + r];
        #pragma unroll
        for (int s = 0; s < 8; ++s) {
            int col = s * 16 + l15;
            #pragma unroll
            for (int r = 0; r < 4; ++r) {
                float v;
                if (s < 2) {                        // col < 32: atom-type embed
                    v = atom_embed[an[r] * 32 + col];
                } else {                            // col >= 32: position MLP
                    int j = col - 32;
                    v = pos_b[j];
                    #pragma unroll
                    for (int c = 0; c < 3; ++c)
                        v = fmaf(spos[(rbase + r) * 3 + c], pos_W[c * 96 + j], v);
                }
                hreg[s][r] = v;
                sm.T3[sidx(rbase + r, col)] = f2bf(v);
            }
        }
    }
    __syncthreads();

    #pragma unroll 1
    for (int l = 0; l < 4; ++l) {
        const ushort_t* wl = wimg + l * IMG_L;
        const float* mb  = msg_b + l * H_;
        const float* ub  = upd_b + l * H_;
        const float* gb  = g_b + l * H_;
        const float* fb  = fus_b + l * H_;
        const float* lg  = ln_g + l * H_;
        const float* lb  = ln_b + l * H_;
        const float* c1b = cb_b1 + l * 4 * H_;
        const float* c2b = cb_b2 + l * H_;

        // A: hmean partials over own 16 rows (from hreg)
        #pragma unroll
        for (int s = 0; s < 8; ++s) {
            int col = s * 16 + l15;
            float p = hreg[s][0] + hreg[s][1] + hreg[s][2] + hreg[s][3];
            p += __shfl_xor(p, 16);
            p += __shfl_xor(p, 32);
            if (quad == 0) part[wave * 128 + col] = f2bf(p);
        }
        __syncthreads();                                 // B1
        if (tid < H_)
            hmean[tid] = (bf2f(part[tid]) + bf2f(part[128 + tid])
                        + bf2f(part[256 + tid]) + bf2f(part[384 + tid])) * (1.0f / 64.0f);
        __syncthreads();                                 // B2

        // C: gvec GEMV (tid<128) ; a_h from T3 ; WI -> T1 (+mb) ; WJ -> T2
        if (tid < H_) {
            float s = gb[tid];
            const ushort_t* wrow = wl + IMG_GMT + tid * 128;
            for (int c = 0; c < 128; c += 8) {
                short8 w = *(const short8*)(wrow + c);
                #pragma unroll
                for (int i = 0; i < 8; ++i) s = fmaf(hmean[c + i], bf2f((ushort_t)w[i]), s);
            }
            gvec[tid] = s;
        }
        {
            short8 a_h[4]; loadA(sm.T3, mrow, quad, a_h);
            #pragma unroll
            for (int s = 0; s < 8; ++s) {
                f32x4 c = gemm_s(a_h, wl + IMG_WI, s, l15, quad);
                int col = s * 16 + l15; float bv = mb[col];
                #pragma unroll
                for (int r = 0; r < 4; ++r)
                    sm.T1[sidx(rbase + r, col)] = f2bf(c[r] + bv);
            }
            #pragma unroll
            for (int s = 0; s < 8; ++s) {
                f32x4 c = gemm_s(a_h, wl + IMG_WJ, s, l15, quad);
                int col = s * 16 + l15;
                #pragma unroll
                for (int r = 0; r < 4; ++r)
                    sm.T2[sidx(rbase + r, col)] = f2bf(c[r]);
            }
        }
        __syncthreads();                                 // B3 (Gm visible to all)

        // D: msum — whole wave per atom n = wave*16+g (own rows), in place in T1
        {
            float ccv[8];
            #pragma unroll
            for (int j = 0; j < 8; ++j)
                ccv[j] = (float)((double)(quad * 8 + j) * (5.0 / 19.0));
            #pragma unroll 1
            for (int g = 0; g < 16; ++g) {
                int n = wave * 16 + g;
                int jv[4]; float ev[4];
                #pragma unroll
                for (int r = 0; r < 4; ++r) {
                    int k = quad * 4 + r;
                    jv[r] = sm.idx[n * 16 + k];
                    ev[r] = sm.env[n * 16 + k];
                }
                float ddm = sm.d[n * 16 + l15];
                short8 arb;
                #pragma unroll
                for (int j = 0; j < 8; ++j) {
                    float t2 = ddm - ccv[j];
                    float rv = __expf(-10.0f * t2 * t2);
                    arb[j] = (short)((quad * 8 + j) < 20 ? f2bf(rv) : (ushort_t)0);
                }
                #pragma unroll
                for (int s = 0; s < 8; ++s) {
                    int col = s * 16 + l15;
                    const ushort_t* rbase_p = wl + IMG_RW + ((s >> 1) << 10)
                                            + ((((s & 1) << 4) + l15) << 5) + quad * 8;
                    short8 brw = *(const short8*)rbase_p;
                    f32x4 c = {0.f, 0.f, 0.f, 0.f};
                    c = __builtin_amdgcn_mfma_f32_16x16x32_bf16(arb, brw, c, 0, 0, 0);
                    float ai = bf2f(sm.T1[sidx(n, col)]);
                    float acc = 0.f;
                    #pragma unroll
                    for (int r = 0; r < 4; ++r) {
                        float gm = bf2f(sm.T2[sidx(jv[r], col)]);
                        acc = fmaf(siluf(ai + gm + c[r]), ev[r], acc);
                    }
                    acc += __shfl_xor(acc, 16);
                    acc += __shfl_xor(acc, 32);
                    if (quad == 0) sm.T1[sidx(n, col)] = f2bf(acc);
                }
            }
        }
        __syncthreads();                                 // B4 (Gm reads done; T2 free)

        // ---- free-run region: everything below touches only own rows ----

        // F: UW(a_m)+hreg -> T2 local ; GS(a_h reloaded from T3) + gvec -> T1 glob
        {
            short8 a_m[4]; loadA(sm.T1, mrow, quad, a_m);
            #pragma unroll
            for (int s = 0; s < 8; ++s) {
                f32x4 c = gemm_s(a_m, wl + IMG_UW, s, l15, quad);
                int col = s * 16 + l15; float bv = ub[col];
                #pragma unroll
                for (int r = 0; r < 4; ++r)
                    sm.T2[sidx(rbase + r, col)] = f2bf(hreg[s][r] + siluf(c[r] + bv));
            }
            short8 a_h[4]; loadA(sm.T3, mrow, quad, a_h);
            #pragma unroll
            for (int s = 0; s < 8; ++s) {
                f32x4 c = gemm_s(a_h, wl + IMG_GS, s, l15, quad);
                int col = s * 16 + l15; float gv = gvec[col];
                #pragma unroll
                for (int r = 0; r < 4; ++r)
                    sm.T1[sidx(rbase + r, col)] = f2bf(siluf(c[r] + gv));
            }
        }

        // G: fused = silu([local|glob]@[FT;FB]+fb) -> hreg ; LN sums in regs
        float sr[4] = {0.f, 0.f, 0.f, 0.f}, qr[4] = {0.f, 0.f, 0.f, 0.f};
        {
            short8 a_t[4];
            loadA(sm.T2, mrow, quad, a_t);               // local
            #pragma unroll
            for (int s = 0; s < 8; ++s) {
                f32x4 c = gemm_s(a_t, wl + IMG_FT, s, l15, quad);
                #pragma unroll
                for (int r = 0; r < 4; ++r) hreg[s][r] = c[r];  // residual h is dead here
            }
            loadA(sm.T1, mrow, quad, a_t);               // glob
            #pragma unroll
            for (int s = 0; s < 8; ++s) {
                f32x4 c = gemm_s(a_t, wl + IMG_FB, s, l15, quad);
                int col = s * 16 + l15; float bv = fb[col];
                #pragma unroll
                for (int r = 0; r < 4; ++r) {
                    float v = siluf(hreg[s][r] + c[r] + bv);
                    hreg[s][r] = v;
                    sr[r] += v; qr[r] += v * v;
                }
            }
            #pragma unroll
            for (int o = 1; o < 16; o <<= 1) {
                #pragma unroll
                for (int r = 0; r < 4; ++r) {
                    sr[r] += __shfl_xor(sr[r], o);
                    qr[r] += __shfl_xor(qr[r], o);
                }
            }
        }

        // H: LN normalize (wave-local) -> T1 (x-hat)
        #pragma unroll
        for (int r = 0; r < 4; ++r) {
            float mu = sr[r] * (1.0f / 128.0f);
            float var = qr[r] * (1.0f / 128.0f) - mu * mu;
            float rs = rsqrtf(var + 1e-5f);
            int row = rbase + r;
            #pragma unroll
            for (int s = 0; s < 8; ++s) {
                int col = s * 16 + l15;
                sm.T1[sidx(row, col)] = f2bf((hreg[s][r] - mu) * rs * lg[col] + lb[col]);
            }
        }

        // J: Clifford MLP, 4 K-chunks; C1 -> T2; C2 accumulates into acc2.
        // acc2 SEEDED with residual + c2b (hreg dead across j-loop); a_x
        // reloaded from T1 each chunk (no 16-reg persistence).
        {
            f32x4 acc2[8];
            #pragma unroll
            for (int s = 0; s < 8; ++s) {
                int col = s * 16 + l15; float bv = c2b[col];
                #pragma unroll
                for (int r = 0; r < 4; ++r) acc2[s][r] = hreg[s][r] + bv;
            }
            #pragma unroll 1
            for (int j = 0; j < 4; ++j) {
                short8 a_x[4]; loadA(sm.T1, mrow, quad, a_x);
                #pragma unroll
                for (int s = 0; s < 8; ++s) {
                    f32x4 c = gemm_s(a_x, wl + IMG_C1 + j * 16384, s, l15, quad);
                    int col = s * 16 + l15; float bv = c1b[j * H_ + col];
                    #pragma unroll
                    for (int r = 0; r < 4; ++r)
                        sm.T2[sidx(rbase + r, col)] = f2bf(siluf(c[r] + bv));
                }
                short8 a_t[4]; loadA(sm.T2, mrow, quad, a_t);
                #pragma unroll
                for (int s = 0; s < 8; ++s)
                    acc2[s] = gemm_s_acc(a_t, wl + IMG_C2 + j * 16384, s, l15, quad, acc2[s]);
            }
            // K: h_next = acc2 (residual+bias already inside) -> hreg + T3 image
            #pragma unroll
            for (int s = 0; s < 8; ++s) {
                #pragma unroll
                for (int r = 0; r < 4; ++r) {
                    float v = acc2[s][r];
                    hreg[s][r] = v;
                    sm.T3[sidx(rbase + r, s * 16 + l15)] = f2bf(v);
                }
            }
        }
        // no layer-end barrier: next stage A reads only own rows/regs
    }

    // ---- head: FO -> T2 (own rows, no barrier) ; barrier ; gather -> out ----
    {
        short8 a_f[4]; loadA(sm.T3, mrow, quad, a_f);
        #pragma unroll
        for (int s = 0; s < 8; ++s) {
            f32x4 c = gemm_s(a_f, wimg + IMG_FO, s, l15, quad);
            int col = s * 16 + l15; float bv = fo_b1[col];
            #pragma unroll
            for (int r = 0; r < 4; ++r)
                sm.T2[sidx(rbase + r, col)] = f2bf(siluf(c[r] + bv));
        }
    }
    __syncthreads();
    if (tid < 192) {
        int n = tid / 3, j = tid - n * 3;
        float s = fo_b2[j];
        #pragma unroll 1
        for (int ch = 0; ch < 16; ++ch) {
            short8 v = *(const short8*)&sm.T2[fragoff(n, ch)];
            #pragma unroll
            for (int i = 0; i < 8; ++i)
                s = fmaf(bf2f((ushort_t)v[i]), fo_W2[(ch * 8 + i) * 3 + j], s);
        }
        out[b * 192 + tid] = s;
    }
}

extern "C" void kernel_launch(void* const* d_in, const int* in_sizes, int n_in,
                              void* d_out, int out_size, void* d_ws, size_t ws_size,
                              hipStream_t stream) {
    (void)in_sizes; (void)n_in; (void)out_size; (void)ws_size;
    convert_weights<<<248, 256, 0, stream>>>(
        (const float*)d_in[5], (const float*)d_in[7], (const float*)d_in[9],
        (const float*)d_in[12], (const float*)d_in[16], (const float*)d_in[18],
        (const float*)d_in[10], (const float*)d_in[20], (ushort_t*)d_ws);
    knn_kernel<<<B_, 64, 0, stream>>>((const float*)d_in[0], (char*)d_ws);
    md17_fused_kernel<<<B_, NT, 0, stream>>>(
        (const float*)d_in[0], (const int*)d_in[1],
        (const float*)d_in[2], (const float*)d_in[3], (const float*)d_in[4],
        (const float*)d_in[6], (const float*)d_in[8],
        (const float*)d_in[11], (const float*)d_in[13],
        (const float*)d_in[14], (const float*)d_in[15],
        (const float*)d_in[17], (const float*)d_in[19],
        (const float*)d_in[21],
        (const float*)d_in[22], (const float*)d_in[23],
        (char*)d_ws, (float*)d_out);
}

// Round 4
// 1346.794 us; speedup vs baseline: 1.5749x; 1.0646x over previous
//
#include <hip/hip_runtime.h>

typedef unsigned short ushort_t;
typedef unsigned int uint_t;
typedef unsigned long long ull_t;
typedef __attribute__((ext_vector_type(8))) short short8;
typedef __attribute__((ext_vector_type(4))) float f32x4;

#define B_ 1024
#define N_ 64
#define H_ 128
#define NT 256

// bf16 weight-image element offsets
#define IMG_WI 0
#define IMG_WJ 16384
#define IMG_UW 32768
#define IMG_GS 49152
#define IMG_FT 65536
#define IMG_FB 81920
#define IMG_C1 98304
#define IMG_C2 163840
#define IMG_GMT 229376
#define IMG_RW 245760
#define IMG_L 249856
#define IMG_FO 999424

__device__ __forceinline__ ushort_t f2bf(float f) {
    // native RNE f32->bf16 (v_cvt_pk_bf16_f32 on gfx950); bit-identical to
    // the integer round-to-nearest-even sequence used previously.
    return __builtin_bit_cast(ushort_t, (__bf16)f);
}
__device__ __forceinline__ float bf2f(ushort_t u) {
    union { uint_t i; float f; } v; v.i = ((uint_t)u) << 16; return v.f;
}
__device__ __forceinline__ float siluf(float x) { return x / (1.0f + __expf(-x)); }

// LDS swizzle: 16B-chunk c of row m stored at chunk c ^ (m&7)
__device__ __forceinline__ int sidx(int m, int k) {
    return m * H_ + (((k >> 3) ^ (m & 7)) << 3) + (k & 7);
}
__device__ __forceinline__ int fragoff(int m, int ch) {
    return m * H_ + ((ch ^ (m & 7)) << 3);
}

// ========== preamble: f32 weights -> transposed bf16 images ==============
// v2: LDS 128x32 tile transpose. Reads coalesced (32x4B rows), writes
// vectorized 2x16B per thread (was 16 scattered 4B reads / 2B writes).
extern "C" __global__ __launch_bounds__(256)
void convert_weights(const float* __restrict__ msg_W, const float* __restrict__ upd_W,
                     const float* __restrict__ gself_W, const float* __restrict__ fus_W,
                     const float* __restrict__ cb_W1, const float* __restrict__ cb_W2,
                     const float* __restrict__ gmean_W, const float* __restrict__ fo_W1,
                     ushort_t* __restrict__ wimg)
{
    __shared__ ushort_t tile[128][34];
    const int g = blockIdx.x;
    const int tid = threadIdx.x;
    const float* W; int ld = 128, k0 = 0, c0; ushort_t* dst;
    if (g >= 244) {
        int st = g - 244;
        W = fo_W1; c0 = st * 32; dst = wimg + IMG_FO + st * 4096;
    } else {
        const int l = g / 61, r = g - l * 61;
        ushort_t* base = wimg + l * IMG_L;
        if (r == 60) {                   // rW pad image: 4 sub-stages [32f][32k]
            const float* Wr = msg_W + l * 35328 + 256 * 128;
            ushort_t* drw = base + IMG_RW;
            for (int e = 0; e < 16; ++e) {
                int q = threadIdx.x * 16 + e;
                int sub = q >> 10, n = (q >> 5) & 31, k = q & 31;
                drw[q] = f2bf(k < 20 ? Wr[(size_t)k * 128 + sub * 32 + n] : 0.0f);
            }
            return;
        }
        int off, st;
        if      (r < 4)  { W = msg_W + l * 35328;            st = r;      off = IMG_WI;  c0 = st * 32; }
        else if (r < 8)  { W = msg_W + l * 35328;  k0 = 128; st = r - 4;  off = IMG_WJ;  c0 = st * 32; }
        else if (r < 12) { W = upd_W + l * 16384;            st = r - 8;  off = IMG_UW;  c0 = st * 32; }
        else if (r < 16) { W = gself_W + l * 16384;          st = r - 12; off = IMG_GS;  c0 = st * 32; }
        else if (r < 20) { W = fus_W + l * 32768;            st = r - 16; off = IMG_FT;  c0 = st * 32; }
        else if (r < 24) { W = fus_W + l * 32768;  k0 = 128; st = r - 20; off = IMG_FB;  c0 = st * 32; }
        else if (r < 40) { W = cb_W1 + l * 65536;  ld = 512; st = r - 24; off = IMG_C1;  c0 = st * 32; }
        else if (r < 56) { int j = (r - 40) >> 2; W = cb_W2 + l * 65536; k0 = j * 128;
                           st = r - 40; off = IMG_C2; c0 = ((r - 40) & 3) * 32; }
        else             { W = gmean_W + l * 16384;          st = r - 56; off = IMG_GMT; c0 = st * 32; }
        dst = base + off + st * 4096;
    }
    const int kr = tid >> 5, n = tid & 31;
    #pragma unroll
    for (int p = 0; p < 16; ++p) {
        int k = p * 8 + kr;
        tile[k][n] = f2bf(W[(size_t)(k0 + k) * ld + c0 + n]);
    }
    __syncthreads();
    {
        int n2 = tid >> 3, kk = (tid & 7) << 4;
        short8 v0, v1;
        #pragma unroll
        for (int e = 0; e < 8; ++e) v0[e] = (short)tile[kk + e][n2];
        #pragma unroll
        for (int e = 0; e < 8; ++e) v1[e] = (short)tile[kk + 8 + e][n2];
        *(short8*)(dst + n2 * 128 + kk) = v0;
        *(short8*)(dst + n2 * 128 + kk + 8) = v1;
    }
}

// ========== main fused kernel ==============================================
// 256 threads = 4 waves; wave w owns rows w*16..w*16+15 (ALL 128 cols).
// kNN is INLINED (per-graph-private; wave w computes atoms w*16..+15 straight
// into LDS) -- the standalone knn kernel (1024 1-wave blocks, ~serial
// selection) and its 12MB workspace round-trip are gone.
// Residual stream in REGISTERS (hreg[8][4], C-frag layout). T3 = layer-input
// h image. __launch_bounds__(NT,2): arch cap 128 (known ~30MB scratch spill,
// accepted; (NT,3)->84-reg cap spilled 8x worse, uncapped -> 1 block/CU).
struct __align__(16) Smem {
    ushort_t T1[N_ * H_];   // 16384B  scratch image (Gm/msum/glob/xhat)
    ushort_t T2[N_ * H_];   // 16384B  scratch image (hj/local/C1)
    ushort_t T3[N_ * H_];   // 16384B  layer-input h image
    float d[1024];          //  4096B
    float env[1024];        //  4096B
    ushort_t idx[1024];     //  2048B
    char u[2048];           // union: spos(768) | {part bf16 1024, hmean 512, gvec 512}
};

// one output stage s (16 cols, col = s*16+l15), K=128: 4 B-frags from global
__device__ __forceinline__ f32x4 gemm_s(const short8 a[4], const ushort_t* __restrict__ img,
                                        int s, int l15, int quad)
{
    const ushort_t* base = img + ((s >> 1) << 12) + ((((s & 1) << 4) + l15) << 7) + quad * 8;
    short8 b0 = *(const short8*)(base);
    short8 b1 = *(const short8*)(base + 32);
    short8 b2 = *(const short8*)(base + 64);
    short8 b3 = *(const short8*)(base + 96);
    f32x4 c = {0.f, 0.f, 0.f, 0.f};
    c = __builtin_amdgcn_mfma_f32_16x16x32_bf16(a[0], b0, c, 0, 0, 0);
    c = __builtin_amdgcn_mfma_f32_16x16x32_bf16(a[1], b1, c, 0, 0, 0);
    c = __builtin_amdgcn_mfma_f32_16x16x32_bf16(a[2], b2, c, 0, 0, 0);
    c = __builtin_amdgcn_mfma_f32_16x16x32_bf16(a[3], b3, c, 0, 0, 0);
    return c;
}
__device__ __forceinline__ f32x4 gemm_s_acc(const short8 a[4], const ushort_t* __restrict__ img,
                                            int s, int l15, int quad, f32x4 c)
{
    const ushort_t* base = img + ((s >> 1) << 12) + ((((s & 1) << 4) + l15) << 7) + quad * 8;
    short8 b0 = *(const short8*)(base);
    short8 b1 = *(const short8*)(base + 32);
    short8 b2 = *(const short8*)(base + 64);
    short8 b3 = *(const short8*)(base + 96);
    c = __builtin_amdgcn_mfma_f32_16x16x32_bf16(a[0], b0, c, 0, 0, 0);
    c = __builtin_amdgcn_mfma_f32_16x16x32_bf16(a[1], b1, c, 0, 0, 0);
    c = __builtin_amdgcn_mfma_f32_16x16x32_bf16(a[2], b2, c, 0, 0, 0);
    c = __builtin_amdgcn_mfma_f32_16x16x32_bf16(a[3], b3, c, 0, 0, 0);
    return c;
}
__device__ __forceinline__ void loadA(const ushort_t* __restrict__ X, int mrow, int quad, short8 a[4]) {
    #pragma unroll
    for (int kc = 0; kc < 4; ++kc) a[kc] = *(const short8*)&X[fragoff(mrow, kc * 4 + quad)];
}

extern "C" __global__ __launch_bounds__(NT, 2)
void md17_fused_kernel(
    const float* __restrict__ positions, const int* __restrict__ atomic_numbers,
    const float* __restrict__ atom_embed, const float* __restrict__ pos_W,
    const float* __restrict__ pos_b,
    const float* __restrict__ msg_b, const float* __restrict__ upd_b,
    const float* __restrict__ g_b, const float* __restrict__ fus_b,
    const float* __restrict__ ln_g, const float* __restrict__ ln_b,
    const float* __restrict__ cb_b1, const float* __restrict__ cb_b2,
    const float* __restrict__ fo_b1,
    const float* __restrict__ fo_W2, const float* __restrict__ fo_b2,
    char* __restrict__ ws, float* __restrict__ out)
{
    __shared__ Smem sm;
    const int b = blockIdx.x;
    const int tid = threadIdx.x;
    const int wave = tid >> 6, lane = tid & 63;
    const int quad = lane >> 4, l15 = lane & 15;
    const int mrow = wave * 16 + l15;       // A-frag row (wave-owned)
    const int rbase = wave * 16 + quad * 4; // C-tile row base (wave-owned)

    const ushort_t* wimg = (const ushort_t*)ws;
    float* spos = (float*)sm.u;
    ushort_t* part = (ushort_t*)sm.u;       // [4][128] bf16 hmean partials
    float* hmean = (float*)(sm.u + 1024);
    float* gvec  = (float*)(sm.u + 1536);

    // residual stream, C-frag layout: hreg[s][r] = h[rbase+r][s*16+l15]
    float hreg[8][4];

    // ---- setup: inline kNN (wave-local atoms), positions ----
    {
        float px = positions[b * 192 + lane * 3 + 0];
        float py = positions[b * 192 + lane * 3 + 1];
        float pz = positions[b * 192 + lane * 3 + 2];
        if (tid < 192) spos[tid] = positions[b * 192 + tid];
        #pragma unroll 1
        for (int g = 0; g < 16; ++g) {
            int n = wave * 16 + g;
            float dx = __fsub_rn(__shfl(px, n), px);
            float dy = __fsub_rn(__shfl(py, n), py);
            float dz = __fsub_rn(__shfl(pz, n), pz);
            float d2 = __fadd_rn(__fadd_rn(__fmul_rn(dx, dx), __fmul_rn(dy, dy)), __fmul_rn(dz, dz));
            if (lane == n) d2 = 1e30f;
            float sd = 0.f; int si = 0;
            for (int k = 0; k < 16; ++k) {
                float dmin = d2;
                #pragma unroll
                for (int o = 1; o < 64; o <<= 1) dmin = fminf(dmin, __shfl_xor(dmin, o));
                ull_t mask = __ballot(d2 == dmin);
                int widx = __ffsll(mask) - 1;       // lowest index on ties (= top_k)
                if (lane == widx) d2 = 1e30f;
                if (lane == k) { si = widx; sd = dmin; }
            }
            if (lane < 16) {
                float dd = sqrtf(fmaxf(sd, 1e-12f));
                sm.d[n * 16 + lane] = dd;
                sm.env[n * 16 + lane] = (dd < 5.0f) ? 0.5f * (__cosf(0.62831853071795864769f * dd) + 1.0f) : 0.0f;
                sm.idx[n * 16 + lane] = (ushort_t)si;
            }
        }
    }
    __syncthreads();
    // ---- embeddings, per-lane into hreg + T3 image ----
    {
        int an[4];
        #pragma unroll
        for (int r = 0; r < 4; ++r) an[r] = atomic_numbers[b * N_ + rbase + r];
        #pragma unroll
        for (int s = 0; s < 8; ++s) {
            int col = s * 16 + l15;
            #pragma unroll
            for (int r = 0; r < 4; ++r) {
                float v;
                if (s < 2) {                        // col < 32: atom-type embed
                    v = atom_embed[an[r] * 32 + col];
                } else {                            // col >= 32: position MLP
                    int j = col - 32;
                    v = pos_b[j];
                    #pragma unroll
                    for (int c = 0; c < 3; ++c)
                        v = fmaf(spos[(rbase + r) * 3 + c], pos_W[c * 96 + j], v);
                }
                hreg[s][r] = v;
                sm.T3[sidx(rbase + r, col)] = f2bf(v);
            }
        }
    }
    __syncthreads();
    // layer-0 hmean partials (stage A folded out of the loop)
    #pragma unroll
    for (int s = 0; s < 8; ++s) {
        int col = s * 16 + l15;
        float p = hreg[s][0] + hreg[s][1] + hreg[s][2] + hreg[s][3];
        p += __shfl_xor(p, 16);
        p += __shfl_xor(p, 32);
        if (quad == 0) part[wave * 128 + col] = f2bf(p);
    }

    #pragma unroll 1
    for (int l = 0; l < 4; ++l) {
        const ushort_t* wl = wimg + l * IMG_L;
        const float* mb  = msg_b + l * H_;
        const float* ub  = upd_b + l * H_;
        const float* gb  = g_b + l * H_;
        const float* fb  = fus_b + l * H_;
        const float* lg  = ln_g + l * H_;
        const float* lb  = ln_b + l * H_;
        const float* c1b = cb_b1 + l * 4 * H_;
        const float* c2b = cb_b2 + l * H_;

        __syncthreads();                                 // B1 (part visible)
        if (tid < H_)
            hmean[tid] = (bf2f(part[tid]) + bf2f(part[128 + tid])
                        + bf2f(part[256 + tid]) + bf2f(part[384 + tid])) * (1.0f / 64.0f);
        __syncthreads();                                 // B2

        // C: gvec GEMV (tid<128) ; a_h from T3 ; WI -> T1 (+mb) ; WJ -> T2
        if (tid < H_) {
            float s = gb[tid];
            const ushort_t* wrow = wl + IMG_GMT + tid * 128;
            for (int c = 0; c < 128; c += 8) {
                short8 w = *(const short8*)(wrow + c);
                #pragma unroll
                for (int i = 0; i < 8; ++i) s = fmaf(hmean[c + i], bf2f((ushort_t)w[i]), s);
            }
            gvec[tid] = s;
        }
        {
            short8 a_h[4]; loadA(sm.T3, mrow, quad, a_h);
            #pragma unroll
            for (int s = 0; s < 8; ++s) {
                f32x4 c = gemm_s(a_h, wl + IMG_WI, s, l15, quad);
                int col = s * 16 + l15; float bv = mb[col];
                #pragma unroll
                for (int r = 0; r < 4; ++r)
                    sm.T1[sidx(rbase + r, col)] = f2bf(c[r] + bv);
            }
            #pragma unroll
            for (int s = 0; s < 8; ++s) {
                f32x4 c = gemm_s(a_h, wl + IMG_WJ, s, l15, quad);
                int col = s * 16 + l15;
                #pragma unroll
                for (int r = 0; r < 4; ++r)
                    sm.T2[sidx(rbase + r, col)] = f2bf(c[r]);
            }
        }
        __syncthreads();                                 // B3 (Gm visible to all)

        // D: msum — whole wave per atom n = wave*16+g (own rows), in place in T1
        {
            float ccv[8];
            #pragma unroll
            for (int j = 0; j < 8; ++j)
                ccv[j] = (float)((double)(quad * 8 + j) * (5.0 / 19.0));
            // RW B-fragments depend only on (s, lane): hoist out of g-loop
            short8 brw[8];
            #pragma unroll
            for (int s = 0; s < 8; ++s)
                brw[s] = *(const short8*)(wl + IMG_RW + ((s >> 1) << 10)
                                          + ((((s & 1) << 4) + l15) << 5) + quad * 8);
            #pragma unroll 1
            for (int g = 0; g < 16; ++g) {
                int n = wave * 16 + g;
                int jv[4]; float ev[4];
                #pragma unroll
                for (int r = 0; r < 4; ++r) {
                    int k = quad * 4 + r;
                    jv[r] = sm.idx[n * 16 + k];
                    ev[r] = sm.env[n * 16 + k];
                }
                float ddm = sm.d[n * 16 + l15];
                short8 arb;
                #pragma unroll
                for (int j = 0; j < 8; ++j) {
                    float t2 = ddm - ccv[j];
                    float rv = __expf(-10.0f * t2 * t2);
                    arb[j] = (short)((quad * 8 + j) < 20 ? f2bf(rv) : (ushort_t)0);
                }
                #pragma unroll
                for (int s = 0; s < 8; ++s) {
                    int col = s * 16 + l15;
                    f32x4 c = {0.f, 0.f, 0.f, 0.f};
                    c = __builtin_amdgcn_mfma_f32_16x16x32_bf16(arb, brw[s], c, 0, 0, 0);
                    float ai = bf2f(sm.T1[sidx(n, col)]);
                    float acc = 0.f;
                    #pragma unroll
                    for (int r = 0; r < 4; ++r) {
                        float gm = bf2f(sm.T2[sidx(jv[r], col)]);
                        acc = fmaf(siluf(ai + gm + c[r]), ev[r], acc);
                    }
                    acc += __shfl_xor(acc, 16);
                    acc += __shfl_xor(acc, 32);
                    if (quad == 0) sm.T1[sidx(n, col)] = f2bf(acc);
                }
            }
        }
        __syncthreads();                                 // B4 (Gm reads done; T2 free)

        // ---- free-run region: everything below touches only own rows ----

        // F: UW(a_m)+hreg -> T2 local ; GS(a_h reloaded from T3) + gvec -> T1 glob
        {
            short8 a_m[4]; loadA(sm.T1, mrow, quad, a_m);
            #pragma unroll
            for (int s = 0; s < 8; ++s) {
                f32x4 c = gemm_s(a_m, wl + IMG_UW, s, l15, quad);
                int col = s * 16 + l15; float bv = ub[col];
                #pragma unroll
                for (int r = 0; r < 4; ++r)
                    sm.T2[sidx(rbase + r, col)] = f2bf(hreg[s][r] + siluf(c[r] + bv));
            }
            short8 a_h[4]; loadA(sm.T3, mrow, quad, a_h);
            #pragma unroll
            for (int s = 0; s < 8; ++s) {
                f32x4 c = gemm_s(a_h, wl + IMG_GS, s, l15, quad);
                int col = s * 16 + l15; float gv = gvec[col];
                #pragma unroll
                for (int r = 0; r < 4; ++r)
                    sm.T1[sidx(rbase + r, col)] = f2bf(siluf(c[r] + gv));
            }
        }

        // G: fused = silu([local|glob]@[FT;FB]+fb) -> hreg ; LN sums in regs
        float sr[4] = {0.f, 0.f, 0.f, 0.f}, qr[4] = {0.f, 0.f, 0.f, 0.f};
        {
            short8 a_t[4];
            loadA(sm.T2, mrow, quad, a_t);               // local
            #pragma unroll
            for (int s = 0; s < 8; ++s) {
                f32x4 c = gemm_s(a_t, wl + IMG_FT, s, l15, quad);
                #pragma unroll
                for (int r = 0; r < 4; ++r) hreg[s][r] = c[r];  // residual h is dead here
            }
            loadA(sm.T1, mrow, quad, a_t);               // glob
            #pragma unroll
            for (int s = 0; s < 8; ++s) {
                f32x4 c = gemm_s(a_t, wl + IMG_FB, s, l15, quad);
                int col = s * 16 + l15; float bv = fb[col];
                #pragma unroll
                for (int r = 0; r < 4; ++r) {
                    float v = siluf(hreg[s][r] + c[r] + bv);
                    hreg[s][r] = v;
                    sr[r] += v; qr[r] += v * v;
                }
            }
            #pragma unroll
            for (int o = 1; o < 16; o <<= 1) {
                #pragma unroll
                for (int r = 0; r < 4; ++r) {
                    sr[r] += __shfl_xor(sr[r], o);
                    qr[r] += __shfl_xor(qr[r], o);
                }
            }
        }

        // H: LN normalize (wave-local) -> T1 (x-hat)
        #pragma unroll
        for (int r = 0; r < 4; ++r) {
            float mu = sr[r] * (1.0f / 128.0f);
            float var = qr[r] * (1.0f / 128.0f) - mu * mu;
            float rs = rsqrtf(var + 1e-5f);
            int row = rbase + r;
            #pragma unroll
            for (int s = 0; s < 8; ++s) {
                int col = s * 16 + l15;
                sm.T1[sidx(row, col)] = f2bf((hreg[s][r] - mu) * rs * lg[col] + lb[col]);
            }
        }

        // J: Clifford MLP, 4 K-chunks; C1 -> T2; C2 accumulates into acc2.
        // acc2 SEEDED with residual + c2b (hreg dead across j-loop); a_x
        // reloaded from T1 each chunk (no 16-reg persistence).
        {
            f32x4 acc2[8];
            #pragma unroll
            for (int s = 0; s < 8; ++s) {
                int col = s * 16 + l15; float bv = c2b[col];
                #pragma unroll
                for (int r = 0; r < 4; ++r) acc2[s][r] = hreg[s][r] + bv;
            }
            #pragma unroll 1
            for (int j = 0; j < 4; ++j) {
                short8 a_x[4]; loadA(sm.T1, mrow, quad, a_x);
                #pragma unroll
                for (int s = 0; s < 8; ++s) {
                    f32x4 c = gemm_s(a_x, wl + IMG_C1 + j * 16384, s, l15, quad);
                    int col = s * 16 + l15; float bv = c1b[j * H_ + col];
                    #pragma unroll
                    for (int r = 0; r < 4; ++r)
                        sm.T2[sidx(rbase + r, col)] = f2bf(siluf(c[r] + bv));
                }
                short8 a_t[4]; loadA(sm.T2, mrow, quad, a_t);
                #pragma unroll
                for (int s = 0; s < 8; ++s)
                    acc2[s] = gemm_s_acc(a_t, wl + IMG_C2 + j * 16384, s, l15, quad, acc2[s]);
            }
            // K: h_next = acc2 -> hreg + T3 image ; fold in next-layer hmean
            // partials (old stage A) while acc2 is in registers.
            #pragma unroll
            for (int s = 0; s < 8; ++s) {
                int col = s * 16 + l15;
                float p = 0.f;
                #pragma unroll
                for (int r = 0; r < 4; ++r) {
                    float v = acc2[s][r];
                    hreg[s][r] = v;
                    sm.T3[sidx(rbase + r, col)] = f2bf(v);
                    p += v;
                }
                p += __shfl_xor(p, 16);
                p += __shfl_xor(p, 32);
                if (quad == 0) part[wave * 128 + col] = f2bf(p);
            }
        }
        // no layer-end barrier: B1 at next layer top covers part/T3 visibility
    }

    // ---- head: FO -> T2 (own rows, no barrier) ; barrier ; gather -> out ----
    {
        short8 a_f[4]; loadA(sm.T3, mrow, quad, a_f);
        #pragma unroll
        for (int s = 0; s < 8; ++s) {
            f32x4 c = gemm_s(a_f, wimg + IMG_FO, s, l15, quad);
            int col = s * 16 + l15; float bv = fo_b1[col];
            #pragma unroll
            for (int r = 0; r < 4; ++r)
                sm.T2[sidx(rbase + r, col)] = f2bf(siluf(c[r] + bv));
        }
    }
    __syncthreads();
    if (tid < 192) {
        int n = tid / 3, j = tid - n * 3;
        float s = fo_b2[j];
        #pragma unroll 1
        for (int ch = 0; ch < 16; ++ch) {
            short8 v = *(const short8*)&sm.T2[fragoff(n, ch)];
            #pragma unroll
            for (int i = 0; i < 8; ++i)
                s = fmaf(bf2f((ushort_t)v[i]), fo_W2[(ch * 8 + i) * 3 + j], s);
        }
        out[b * 192 + tid] = s;
    }
}

extern "C" void kernel_launch(void* const* d_in, const int* in_sizes, int n_in,
                              void* d_out, int out_size, void* d_ws, size_t ws_size,
                              hipStream_t stream) {
    (void)in_sizes; (void)n_in; (void)out_size; (void)ws_size;
    convert_weights<<<248, 256, 0, stream>>>(
        (const float*)d_in[5], (const float*)d_in[7], (const float*)d_in[9],
        (const float*)d_in[12], (const float*)d_in[16], (const float*)d_in[18],
        (const float*)d_in[10], (const float*)d_in[20], (ushort_t*)d_ws);
    md17_fused_kernel<<<B_, NT, 0, stream>>>(
        (const float*)d_in[0], (const int*)d_in[1],
        (const float*)d_in[2], (const float*)d_in[3], (const float*)d_in[4],
        (const float*)d_in[6], (const float*)d_in[8],
        (const float*)d_in[11], (const float*)d_in[13],
        (const float*)d_in[14], (const float*)d_in[15],
        (const float*)d_in[17], (const float*)d_in[19],
        (const float*)d_in[21],
        (const float*)d_in[22], (const float*)d_in[23],
        (char*)d_ws, (float*)d_out);
}

// Round 5
// 1203.027 us; speedup vs baseline: 1.7632x; 1.1195x over previous
//
#include <hip/hip_runtime.h>

typedef unsigned short ushort_t;
typedef unsigned int uint_t;
typedef unsigned long long ull_t;
typedef __attribute__((ext_vector_type(8))) short short8;
typedef __attribute__((ext_vector_type(4))) float f32x4;

#define B_ 1024
#define N_ 64
#define H_ 128
#define NT 256

// bf16 weight-image element offsets
#define IMG_WI 0
#define IMG_WJ 16384
#define IMG_UW 32768
#define IMG_GS 49152
#define IMG_FT 65536
#define IMG_FB 81920
#define IMG_C1 98304
#define IMG_C2 163840
#define IMG_GMT 229376
#define IMG_RW 245760
#define IMG_L 249856
#define IMG_FO 999424

__device__ __forceinline__ ushort_t f2bf(float f) {
    // native RNE f32->bf16; bit-identical to the integer RNE sequence.
    return __builtin_bit_cast(ushort_t, (__bf16)f);
}
__device__ __forceinline__ float bf2f(ushort_t u) {
    union { uint_t i; float f; } v; v.i = ((uint_t)u) << 16; return v.f;
}
__device__ __forceinline__ float siluf(float x) { return x / (1.0f + __expf(-x)); }

// LDS swizzle: 16B-chunk c of row m stored at chunk c ^ (m&7)
__device__ __forceinline__ int sidx(int m, int k) {
    return m * H_ + (((k >> 3) ^ (m & 7)) << 3) + (k & 7);
}
__device__ __forceinline__ int fragoff(int m, int ch) {
    return m * H_ + ((ch ^ (m & 7)) << 3);
}

// ========== preamble: f32 weights -> transposed bf16 images ==============
// LDS 128x32 tile transpose. Reads coalesced (32x4B rows), writes
// vectorized 2x16B per thread.
extern "C" __global__ __launch_bounds__(256)
void convert_weights(const float* __restrict__ msg_W, const float* __restrict__ upd_W,
                     const float* __restrict__ gself_W, const float* __restrict__ fus_W,
                     const float* __restrict__ cb_W1, const float* __restrict__ cb_W2,
                     const float* __restrict__ gmean_W, const float* __restrict__ fo_W1,
                     ushort_t* __restrict__ wimg)
{
    __shared__ ushort_t tile[128][34];
    const int g = blockIdx.x;
    const int tid = threadIdx.x;
    const float* W; int ld = 128, k0 = 0, c0; ushort_t* dst;
    if (g >= 244) {
        int st = g - 244;
        W = fo_W1; c0 = st * 32; dst = wimg + IMG_FO + st * 4096;
    } else {
        const int l = g / 61, r = g - l * 61;
        ushort_t* base = wimg + l * IMG_L;
        if (r == 60) {                   // rW pad image: 4 sub-stages [32f][32k]
            const float* Wr = msg_W + l * 35328 + 256 * 128;
            ushort_t* drw = base + IMG_RW;
            for (int e = 0; e < 16; ++e) {
                int q = threadIdx.x * 16 + e;
                int sub = q >> 10, n = (q >> 5) & 31, k = q & 31;
                drw[q] = f2bf(k < 20 ? Wr[(size_t)k * 128 + sub * 32 + n] : 0.0f);
            }
            return;
        }
        int off, st;
        if      (r < 4)  { W = msg_W + l * 35328;            st = r;      off = IMG_WI;  c0 = st * 32; }
        else if (r < 8)  { W = msg_W + l * 35328;  k0 = 128; st = r - 4;  off = IMG_WJ;  c0 = st * 32; }
        else if (r < 12) { W = upd_W + l * 16384;            st = r - 8;  off = IMG_UW;  c0 = st * 32; }
        else if (r < 16) { W = gself_W + l * 16384;          st = r - 12; off = IMG_GS;  c0 = st * 32; }
        else if (r < 20) { W = fus_W + l * 32768;            st = r - 16; off = IMG_FT;  c0 = st * 32; }
        else if (r < 24) { W = fus_W + l * 32768;  k0 = 128; st = r - 20; off = IMG_FB;  c0 = st * 32; }
        else if (r < 40) { W = cb_W1 + l * 65536;  ld = 512; st = r - 24; off = IMG_C1;  c0 = st * 32; }
        else if (r < 56) { int j = (r - 40) >> 2; W = cb_W2 + l * 65536; k0 = j * 128;
                           st = r - 40; off = IMG_C2; c0 = ((r - 40) & 3) * 32; }
        else             { W = gmean_W + l * 16384;          st = r - 56; off = IMG_GMT; c0 = st * 32; }
        dst = base + off + st * 4096;
    }
    const int kr = tid >> 5, n = tid & 31;
    #pragma unroll
    for (int p = 0; p < 16; ++p) {
        int k = p * 8 + kr;
        tile[k][n] = f2bf(W[(size_t)(k0 + k) * ld + c0 + n]);
    }
    __syncthreads();
    {
        int n2 = tid >> 3, kk = (tid & 7) << 4;
        short8 v0, v1;
        #pragma unroll
        for (int e = 0; e < 8; ++e) v0[e] = (short)tile[kk + e][n2];
        #pragma unroll
        for (int e = 0; e < 8; ++e) v1[e] = (short)tile[kk + 8 + e][n2];
        *(short8*)(dst + n2 * 128 + kk) = v0;
        *(short8*)(dst + n2 * 128 + kk + 8) = v1;
    }
}

// ========== main fused kernel ==============================================
// 256 threads = 4 waves; wave w owns rows w*16..w*16+15 (ALL 128 cols).
// kNN inlined, QUAD-PARALLEL: each 16-lane group selects for one atom
// (4 candidates/lane, idx = l15*4+j so lane order = global index order);
// butterflies are xor 1/2/4/8 (intra-row DPP, ~2cy) -- the R4 version's
// whole-wave serial selection (xor16/32 ds_permute chains) cost ~+19us/wave.
// Residual stream in REGISTERS (hreg[8][4], C-frag layout). T3 = layer-input
// h image. __launch_bounds__(NT,2): arch cap 128. s-loops not touching
// hreg/acc2 are unroll-2 to bound B-fragment prefetch depth (spill source).
struct __align__(16) Smem {
    ushort_t T1[N_ * H_];   // 16384B  scratch image (Gm/msum/glob/xhat)
    ushort_t T2[N_ * H_];   // 16384B  scratch image (hj/local/C1)
    ushort_t T3[N_ * H_];   // 16384B  layer-input h image
    float d[1024];          //  4096B
    float env[1024];        //  4096B
    ushort_t idx[1024];     //  2048B
    char u[2048];           // union: spos(768) | {part bf16 1024, hmean 512, gvec 512}
};

// one output stage s (16 cols, col = s*16+l15), K=128: 4 B-frags from global
__device__ __forceinline__ f32x4 gemm_s(const short8 a[4], const ushort_t* __restrict__ img,
                                        int s, int l15, int quad)
{
    const ushort_t* base = img + ((s >> 1) << 12) + ((((s & 1) << 4) + l15) << 7) + quad * 8;
    short8 b0 = *(const short8*)(base);
    short8 b1 = *(const short8*)(base + 32);
    short8 b2 = *(const short8*)(base + 64);
    short8 b3 = *(const short8*)(base + 96);
    f32x4 c = {0.f, 0.f, 0.f, 0.f};
    c = __builtin_amdgcn_mfma_f32_16x16x32_bf16(a[0], b0, c, 0, 0, 0);
    c = __builtin_amdgcn_mfma_f32_16x16x32_bf16(a[1], b1, c, 0, 0, 0);
    c = __builtin_amdgcn_mfma_f32_16x16x32_bf16(a[2], b2, c, 0, 0, 0);
    c = __builtin_amdgcn_mfma_f32_16x16x32_bf16(a[3], b3, c, 0, 0, 0);
    return c;
}
__device__ __forceinline__ f32x4 gemm_s_acc(const short8 a[4], const ushort_t* __restrict__ img,
                                            int s, int l15, int quad, f32x4 c)
{
    const ushort_t* base = img + ((s >> 1) << 12) + ((((s & 1) << 4) + l15) << 7) + quad * 8;
    short8 b0 = *(const short8*)(base);
    short8 b1 = *(const short8*)(base + 32);
    short8 b2 = *(const short8*)(base + 64);
    short8 b3 = *(const short8*)(base + 96);
    c = __builtin_amdgcn_mfma_f32_16x16x32_bf16(a[0], b0, c, 0, 0, 0);
    c = __builtin_amdgcn_mfma_f32_16x16x32_bf16(a[1], b1, c, 0, 0, 0);
    c = __builtin_amdgcn_mfma_f32_16x16x32_bf16(a[2], b2, c, 0, 0, 0);
    c = __builtin_amdgcn_mfma_f32_16x16x32_bf16(a[3], b3, c, 0, 0, 0);
    return c;
}
__device__ __forceinline__ void loadA(const ushort_t* __restrict__ X, int mrow, int quad, short8 a[4]) {
    #pragma unroll
    for (int kc = 0; kc < 4; ++kc) a[kc] = *(const short8*)&X[fragoff(mrow, kc * 4 + quad)];
}

extern "C" __global__ __launch_bounds__(NT, 2)
void md17_fused_kernel(
    const float* __restrict__ positions, const int* __restrict__ atomic_numbers,
    const float* __restrict__ atom_embed, const float* __restrict__ pos_W,
    const float* __restrict__ pos_b,
    const float* __restrict__ msg_b, const float* __restrict__ upd_b,
    const float* __restrict__ g_b, const float* __restrict__ fus_b,
    const float* __restrict__ ln_g, const float* __restrict__ ln_b,
    const float* __restrict__ cb_b1, const float* __restrict__ cb_b2,
    const float* __restrict__ fo_b1,
    const float* __restrict__ fo_W2, const float* __restrict__ fo_b2,
    char* __restrict__ ws, float* __restrict__ out)
{
    __shared__ Smem sm;
    const int b = blockIdx.x;
    const int tid = threadIdx.x;
    const int wave = tid >> 6, lane = tid & 63;
    const int quad = lane >> 4, l15 = lane & 15;
    const int mrow = wave * 16 + l15;       // A-frag row (wave-owned)
    const int rbase = wave * 16 + quad * 4; // C-tile row base (wave-owned)

    const ushort_t* wimg = (const ushort_t*)ws;
    float* spos = (float*)sm.u;
    ushort_t* part = (ushort_t*)sm.u;       // [4][128] bf16 hmean partials
    float* hmean = (float*)(sm.u + 1024);
    float* gvec  = (float*)(sm.u + 1536);

    // residual stream, C-frag layout: hreg[s][r] = h[rbase+r][s*16+l15]
    float hreg[8][4];

    // ---- setup: positions -> LDS ----
    if (tid < 192) spos[tid] = positions[b * 192 + tid];
    __syncthreads();

    // ---- quad-parallel inline kNN: 16-lane group per atom ----
    {
        // candidates: lane owns atoms l15*4 .. l15*4+3 (lane order = index order)
        float cx[4], cy[4], cz[4];
        #pragma unroll
        for (int j = 0; j < 4; ++j) {
            cx[j] = spos[(l15 * 4 + j) * 3 + 0];
            cy[j] = spos[(l15 * 4 + j) * 3 + 1];
            cz[j] = spos[(l15 * 4 + j) * 3 + 2];
        }
        #pragma unroll 1
        for (int it = 0; it < 4; ++it) {
            const int n = wave * 16 + it * 4 + quad;   // this quad-group's atom
            float nx = spos[n * 3 + 0], ny = spos[n * 3 + 1], nz = spos[n * 3 + 2];
            float d2[4];
            #pragma unroll
            for (int j = 0; j < 4; ++j) {
                float dx = __fsub_rn(nx, cx[j]);
                float dy = __fsub_rn(ny, cy[j]);
                float dz = __fsub_rn(nz, cz[j]);
                d2[j] = __fadd_rn(__fadd_rn(__fmul_rn(dx, dx), __fmul_rn(dy, dy)),
                                  __fmul_rn(dz, dz));
                if (l15 * 4 + j == n) d2[j] = 1e30f;   // exclude self
            }
            #pragma unroll 1
            for (int k = 0; k < 16; ++k) {
                // strict < keeps lowest j on intra-lane ties
                float lm = d2[0];
                if (d2[1] < lm) lm = d2[1];
                if (d2[2] < lm) lm = d2[2];
                if (d2[3] < lm) lm = d2[3];
                float gm = lm;
                #pragma unroll
                for (int o = 1; o < 16; o <<= 1) gm = fminf(gm, __shfl_xor(gm, o));
                ull_t bal = __ballot(lm == gm);
                int wl = __ffsll((bal >> (quad * 16)) & 0xFFFFull) - 1;  // lowest lane
                if (l15 == wl) {
                    int jstar = 3;                      // lowest matching slot
                    if (d2[2] == gm) jstar = 2;
                    if (d2[1] == gm) jstar = 1;
                    if (d2[0] == gm) jstar = 0;
                    #pragma unroll
                    for (int j = 0; j < 4; ++j) if (j == jstar) d2[j] = 1e30f;
                    float dd = sqrtf(fmaxf(gm, 1e-12f));
                    sm.d[n * 16 + k] = dd;
                    sm.env[n * 16 + k] = (dd < 5.0f)
                        ? 0.5f * (__cosf(0.62831853071795864769f * dd) + 1.0f) : 0.0f;
                    sm.idx[n * 16 + k] = (ushort_t)(wl * 4 + jstar);
                }
            }
        }
    }

    // ---- embeddings, per-lane into hreg + T3 image ----
    {
        int an[4];
        #pragma unroll
        for (int r = 0; r < 4; ++r) an[r] = atomic_numbers[b * N_ + rbase + r];
        #pragma unroll
        for (int s = 0; s < 8; ++s) {
            int col = s * 16 + l15;
            #pragma unroll
            for (int r = 0; r < 4; ++r) {
                float v;
                if (s < 2) {                        // col < 32: atom-type embed
                    v = atom_embed[an[r] * 32 + col];
                } else {                            // col >= 32: position MLP
                    int j = col - 32;
                    v = pos_b[j];
                    #pragma unroll
                    for (int c = 0; c < 3; ++c)
                        v = fmaf(spos[(rbase + r) * 3 + c], pos_W[c * 96 + j], v);
                }
                hreg[s][r] = v;
                sm.T3[sidx(rbase + r, col)] = f2bf(v);
            }
        }
    }
    __syncthreads();
    // layer-0 hmean partials (stage A folded out of the loop)
    #pragma unroll
    for (int s = 0; s < 8; ++s) {
        int col = s * 16 + l15;
        float p = hreg[s][0] + hreg[s][1] + hreg[s][2] + hreg[s][3];
        p += __shfl_xor(p, 16);
        p += __shfl_xor(p, 32);
        if (quad == 0) part[wave * 128 + col] = f2bf(p);
    }

    #pragma unroll 1
    for (int l = 0; l < 4; ++l) {
        const ushort_t* wl = wimg + l * IMG_L;
        const float* mb  = msg_b + l * H_;
        const float* ub  = upd_b + l * H_;
        const float* gb  = g_b + l * H_;
        const float* fb  = fus_b + l * H_;
        const float* lg  = ln_g + l * H_;
        const float* lb  = ln_b + l * H_;
        const float* c1b = cb_b1 + l * 4 * H_;
        const float* c2b = cb_b2 + l * H_;

        __syncthreads();                                 // B1 (part visible)
        if (tid < H_)
            hmean[tid] = (bf2f(part[tid]) + bf2f(part[128 + tid])
                        + bf2f(part[256 + tid]) + bf2f(part[384 + tid])) * (1.0f / 64.0f);
        __syncthreads();                                 // B2

        // C: gvec GEMV (tid<128) ; a_h from T3 ; WI -> T1 (+mb) ; WJ -> T2
        if (tid < H_) {
            float s = gb[tid];
            const ushort_t* wrow = wl + IMG_GMT + tid * 128;
            for (int c = 0; c < 128; c += 8) {
                short8 w = *(const short8*)(wrow + c);
                #pragma unroll
                for (int i = 0; i < 8; ++i) s = fmaf(hmean[c + i], bf2f((ushort_t)w[i]), s);
            }
            gvec[tid] = s;
        }
        {
            short8 a_h[4]; loadA(sm.T3, mrow, quad, a_h);
            #pragma unroll 2
            for (int s = 0; s < 8; ++s) {
                f32x4 c = gemm_s(a_h, wl + IMG_WI, s, l15, quad);
                int col = s * 16 + l15; float bv = mb[col];
                #pragma unroll
                for (int r = 0; r < 4; ++r)
                    sm.T1[sidx(rbase + r, col)] = f2bf(c[r] + bv);
            }
            #pragma unroll 2
            for (int s = 0; s < 8; ++s) {
                f32x4 c = gemm_s(a_h, wl + IMG_WJ, s, l15, quad);
                int col = s * 16 + l15;
                #pragma unroll
                for (int r = 0; r < 4; ++r)
                    sm.T2[sidx(rbase + r, col)] = f2bf(c[r]);
            }
        }
        __syncthreads();                                 // B3 (Gm visible to all)

        // D: msum — whole wave per atom n = wave*16+g (own rows), in place in T1
        {
            float ccv[8];
            #pragma unroll
            for (int j = 0; j < 8; ++j)
                ccv[j] = (float)((double)(quad * 8 + j) * (5.0 / 19.0));
            #pragma unroll 1
            for (int g = 0; g < 16; ++g) {
                int n = wave * 16 + g;
                int jv[4]; float ev[4];
                #pragma unroll
                for (int r = 0; r < 4; ++r) {
                    int k = quad * 4 + r;
                    jv[r] = sm.idx[n * 16 + k];
                    ev[r] = sm.env[n * 16 + k];
                }
                float ddm = sm.d[n * 16 + l15];
                short8 arb;
                #pragma unroll
                for (int j = 0; j < 8; ++j) {
                    float t2 = ddm - ccv[j];
                    float rv = __expf(-10.0f * t2 * t2);
                    arb[j] = (short)((quad * 8 + j) < 20 ? f2bf(rv) : (ushort_t)0);
                }
                #pragma unroll
                for (int s = 0; s < 8; ++s) {
                    int col = s * 16 + l15;
                    const ushort_t* rbase_p = wl + IMG_RW + ((s >> 1) << 10)
                                            + ((((s & 1) << 4) + l15) << 5) + quad * 8;
                    short8 brw = *(const short8*)rbase_p;
                    f32x4 c = {0.f, 0.f, 0.f, 0.f};
                    c = __builtin_amdgcn_mfma_f32_16x16x32_bf16(arb, brw, c, 0, 0, 0);
                    float ai = bf2f(sm.T1[sidx(n, col)]);
                    float acc = 0.f;
                    #pragma unroll
                    for (int r = 0; r < 4; ++r) {
                        float gm = bf2f(sm.T2[sidx(jv[r], col)]);
                        acc = fmaf(siluf(ai + gm + c[r]), ev[r], acc);
                    }
                    acc += __shfl_xor(acc, 16);
                    acc += __shfl_xor(acc, 32);
                    if (quad == 0) sm.T1[sidx(n, col)] = f2bf(acc);
                }
            }
        }
        __syncthreads();                                 // B4 (Gm reads done; T2 free)

        // ---- free-run region: everything below touches only own rows ----

        // F: UW(a_m)+hreg -> T2 local ; GS(a_h reloaded from T3) + gvec -> T1 glob
        {
            short8 a_m[4]; loadA(sm.T1, mrow, quad, a_m);
            #pragma unroll
            for (int s = 0; s < 8; ++s) {
                f32x4 c = gemm_s(a_m, wl + IMG_UW, s, l15, quad);
                int col = s * 16 + l15; float bv = ub[col];
                #pragma unroll
                for (int r = 0; r < 4; ++r)
                    sm.T2[sidx(rbase + r, col)] = f2bf(hreg[s][r] + siluf(c[r] + bv));
            }
            short8 a_h[4]; loadA(sm.T3, mrow, quad, a_h);
            #pragma unroll 2
            for (int s = 0; s < 8; ++s) {
                f32x4 c = gemm_s(a_h, wl + IMG_GS, s, l15, quad);
                int col = s * 16 + l15; float gv = gvec[col];
                #pragma unroll
                for (int r = 0; r < 4; ++r)
                    sm.T1[sidx(rbase + r, col)] = f2bf(siluf(c[r] + gv));
            }
        }

        // G: fused = silu([local|glob]@[FT;FB]+fb) -> hreg ; LN sums in regs
        float sr[4] = {0.f, 0.f, 0.f, 0.f}, qr[4] = {0.f, 0.f, 0.f, 0.f};
        {
            short8 a_t[4];
            loadA(sm.T2, mrow, quad, a_t);               // local
            #pragma unroll
            for (int s = 0; s < 8; ++s) {
                f32x4 c = gemm_s(a_t, wl + IMG_FT, s, l15, quad);
                #pragma unroll
                for (int r = 0; r < 4; ++r) hreg[s][r] = c[r];  // residual h is dead here
            }
            loadA(sm.T1, mrow, quad, a_t);               // glob
            #pragma unroll
            for (int s = 0; s < 8; ++s) {
                f32x4 c = gemm_s(a_t, wl + IMG_FB, s, l15, quad);
                int col = s * 16 + l15; float bv = fb[col];
                #pragma unroll
                for (int r = 0; r < 4; ++r) {
                    float v = siluf(hreg[s][r] + c[r] + bv);
                    hreg[s][r] = v;
                    sr[r] += v; qr[r] += v * v;
                }
            }
            #pragma unroll
            for (int o = 1; o < 16; o <<= 1) {
                #pragma unroll
                for (int r = 0; r < 4; ++r) {
                    sr[r] += __shfl_xor(sr[r], o);
                    qr[r] += __shfl_xor(qr[r], o);
                }
            }
        }

        // H: LN normalize (wave-local) -> T1 (x-hat)
        #pragma unroll
        for (int r = 0; r < 4; ++r) {
            float mu = sr[r] * (1.0f / 128.0f);
            float var = qr[r] * (1.0f / 128.0f) - mu * mu;
            float rs = rsqrtf(var + 1e-5f);
            int row = rbase + r;
            #pragma unroll
            for (int s = 0; s < 8; ++s) {
                int col = s * 16 + l15;
                sm.T1[sidx(row, col)] = f2bf((hreg[s][r] - mu) * rs * lg[col] + lb[col]);
            }
        }

        // J: Clifford MLP, 4 K-chunks; C1 -> T2; C2 accumulates into acc2.
        // acc2 SEEDED with residual + c2b (hreg dead across j-loop); a_x
        // reloaded from T1 each chunk (no 16-reg persistence).
        {
            f32x4 acc2[8];
            #pragma unroll
            for (int s = 0; s < 8; ++s) {
                int col = s * 16 + l15; float bv = c2b[col];
                #pragma unroll
                for (int r = 0; r < 4; ++r) acc2[s][r] = hreg[s][r] + bv;
            }
            #pragma unroll 1
            for (int j = 0; j < 4; ++j) {
                short8 a_x[4]; loadA(sm.T1, mrow, quad, a_x);
                #pragma unroll 2
                for (int s = 0; s < 8; ++s) {
                    f32x4 c = gemm_s(a_x, wl + IMG_C1 + j * 16384, s, l15, quad);
                    int col = s * 16 + l15; float bv = c1b[j * H_ + col];
                    #pragma unroll
                    for (int r = 0; r < 4; ++r)
                        sm.T2[sidx(rbase + r, col)] = f2bf(siluf(c[r] + bv));
                }
                short8 a_t[4]; loadA(sm.T2, mrow, quad, a_t);
                #pragma unroll
                for (int s = 0; s < 8; ++s)
                    acc2[s] = gemm_s_acc(a_t, wl + IMG_C2 + j * 16384, s, l15, quad, acc2[s]);
            }
            // K: h_next = acc2 -> hreg + T3 image ; fold next-layer hmean partials
            #pragma unroll
            for (int s = 0; s < 8; ++s) {
                int col = s * 16 + l15;
                float p = 0.f;
                #pragma unroll
                for (int r = 0; r < 4; ++r) {
                    float v = acc2[s][r];
                    hreg[s][r] = v;
                    sm.T3[sidx(rbase + r, col)] = f2bf(v);
                    p += v;
                }
                p += __shfl_xor(p, 16);
                p += __shfl_xor(p, 32);
                if (quad == 0) part[wave * 128 + col] = f2bf(p);
            }
        }
        // no layer-end barrier: B1 at next layer top covers part/T3 visibility
    }

    // ---- head: FO -> T2 (own rows, no barrier) ; barrier ; gather -> out ----
    {
        short8 a_f[4]; loadA(sm.T3, mrow, quad, a_f);
        #pragma unroll 2
        for (int s = 0; s < 8; ++s) {
            f32x4 c = gemm_s(a_f, wimg + IMG_FO, s, l15, quad);
            int col = s * 16 + l15; float bv = fo_b1[col];
            #pragma unroll
            for (int r = 0; r < 4; ++r)
                sm.T2[sidx(rbase + r, col)] = f2bf(siluf(c[r] + bv));
        }
    }
    __syncthreads();
    if (tid < 192) {
        int n = tid / 3, j = tid - n * 3;
        float s = fo_b2[j];
        #pragma unroll 1
        for (int ch = 0; ch < 16; ++ch) {
            short8 v = *(const short8*)&sm.T2[fragoff(n, ch)];
            #pragma unroll
            for (int i = 0; i < 8; ++i)
                s = fmaf(bf2f((ushort_t)v[i]), fo_W2[(ch * 8 + i) * 3 + j], s);
        }
        out[b * 192 + tid] = s;
    }
}

extern "C" void kernel_launch(void* const* d_in, const int* in_sizes, int n_in,
                              void* d_out, int out_size, void* d_ws, size_t ws_size,
                              hipStream_t stream) {
    (void)in_sizes; (void)n_in; (void)out_size; (void)ws_size;
    convert_weights<<<248, 256, 0, stream>>>(
        (const float*)d_in[5], (const float*)d_in[7], (const float*)d_in[9],
        (const float*)d_in[12], (const float*)d_in[16], (const float*)d_in[18],
        (const float*)d_in[10], (const float*)d_in[20], (ushort_t*)d_ws);
    md17_fused_kernel<<<B_, NT, 0, stream>>>(
        (const float*)d_in[0], (const int*)d_in[1],
        (const float*)d_in[2], (const float*)d_in[3], (const float*)d_in[4],
        (const float*)d_in[6], (const float*)d_in[8],
        (const float*)d_in[11], (const float*)d_in[13],
        (const float*)d_in[14], (const float*)d_in[15],
        (const float*)d_in[17], (const float*)d_in[19],
        (const float*)d_in[21],
        (const float*)d_in[22], (const float*)d_in[23],
        (char*)d_ws, (float*)d_out);
}